// Round 10
// baseline (1780.368 us; speedup 1.0000x reference)
//
#include <hip/hip_runtime.h>
#include <hip/hip_bf16.h>
#include <stdint.h>

#define LNUM 6
#define BB 8
#define TT 1024
#define CC 768
#define HH 12
#define HDIM 64
#define DFF 3072
#define VV 512
#define MM (BB*TT)
#define QKREG ((size_t)BB*HH*TT*64)

typedef __bf16 bf16x8 __attribute__((ext_vector_type(8)));
typedef float f32x4 __attribute__((ext_vector_type(4)));

__device__ __forceinline__ uint16_t f2b(float f) {
  uint32_t u = __float_as_uint(f);
  u += 0x7FFFu + ((u >> 16) & 1u);
  return (uint16_t)(u >> 16);
}

__device__ __forceinline__ float b2f(uint16_t u) {
  return __uint_as_float((uint32_t)u << 16);
}

__device__ __forceinline__ void gld16(const uint16_t* g, uint16_t* l) {
  __builtin_amdgcn_global_load_lds(
      (const __attribute__((address_space(1))) uint32_t*)g,
      (__attribute__((address_space(3))) uint32_t*)l, 16, 0, 0);
}

__device__ __forceinline__ f32x4 mfma16(bf16x8 a, bf16x8 b, f32x4 c) {
  return __builtin_amdgcn_mfma_f32_16x16x32_bf16(a, b, c, 0, 0, 0);
}

// ---------------- convert f32 -> bf16 ----------------
__global__ __launch_bounds__(256) void cvt4_k(const float* __restrict__ in,
                                              uint16_t* __restrict__ out, int n4) {
  const int gid = blockIdx.x * 256 + threadIdx.x;
  if (gid >= n4) return;
  const float4 v = ((const float4*)in)[gid];
  ushort4 w; w.x = f2b(v.x); w.y = f2b(v.y); w.z = f2b(v.z); w.w = f2b(v.w);
  ((ushort4*)out)[gid] = w;
}

// ---------------- embedding ----------------
__global__ __launch_bounds__(256) void embed_k(const int* __restrict__ idx,
                                               const float* __restrict__ tok,
                                               const float* __restrict__ pos,
                                               float* __restrict__ x) {
  const int gid = blockIdx.x * 256 + threadIdx.x;
  const int row = gid / (CC / 4), c4 = gid % (CC / 4);
  const int t = row & (TT - 1);
  const int tkn = idx[row];
  const float4 a = ((const float4*)(tok + (size_t)tkn * CC))[c4];
  const float4 q = ((const float4*)(pos + (size_t)t * CC))[c4];
  ((float4*)(x + (size_t)row * CC))[c4] =
      make_float4(a.x + q.x, a.y + q.y, a.z + q.z, a.w + q.w);
}

// ---------------- layernorm: fp32 in -> bf16 out ----------------
__global__ __launch_bounds__(256) void ln_k(const float* __restrict__ x,
                                            const float* __restrict__ gamma,
                                            const float* __restrict__ beta,
                                            uint16_t* __restrict__ o) {
  const int lane = threadIdx.x & 63, wid = threadIdx.x >> 6;
  const int row = blockIdx.x * 4 + wid;
  const float4* xr = (const float4*)(x + (size_t)row * CC);
  float4 v[3]; float s = 0.f, sq = 0.f;
#pragma unroll
  for (int i = 0; i < 3; ++i) {
    v[i] = xr[lane + i * 64];
    s += v[i].x + v[i].y + v[i].z + v[i].w;
    sq += v[i].x * v[i].x + v[i].y * v[i].y + v[i].z * v[i].z + v[i].w * v[i].w;
  }
#pragma unroll
  for (int m = 1; m < 64; m <<= 1) { s += __shfl_xor(s, m, 64); sq += __shfl_xor(sq, m, 64); }
  const float mu = s * (1.f / 768.f);
  const float rstd = rsqrtf(sq * (1.f / 768.f) - mu * mu + 1e-5f);
  ushort4* orow = (ushort4*)(o + (size_t)row * CC);
#pragma unroll
  for (int i = 0; i < 3; ++i) {
    const int c4 = lane + i * 64;
    const float4 gg = ((const float4*)gamma)[c4];
    const float4 bb = ((const float4*)beta)[c4];
    ushort4 w;
    w.x = f2b((v[i].x - mu) * rstd * gg.x + bb.x);
    w.y = f2b((v[i].y - mu) * rstd * gg.y + bb.y);
    w.z = f2b((v[i].z - mu) * rstd * gg.z + bb.z);
    w.w = f2b((v[i].w - mu) * rstd * gg.w + bb.w);
    orow[c4] = w;
  }
}

// ------- layernorm + NP bf16-partial reduce: x += sum(p_j); o = LN(x) -------
template <int NP>
__global__ __launch_bounds__(256) void lnrb_k(float* __restrict__ x,
                                              const uint16_t* __restrict__ pp,
                                              const float* __restrict__ gamma,
                                              const float* __restrict__ beta,
                                              uint16_t* __restrict__ o) {
  const int lane = threadIdx.x & 63, wid = threadIdx.x >> 6;
  const int row = blockIdx.x * 4 + wid;
  float4* xr = (float4*)(x + (size_t)row * CC);
  float4 v[3]; float s = 0.f, sq = 0.f;
#pragma unroll
  for (int i = 0; i < 3; ++i) {
    const int c4 = lane + i * 64;
    float4 a = xr[c4];
#pragma unroll
    for (int j = 0; j < NP; ++j) {
      const ushort4 q =
          ((const ushort4*)(pp + (size_t)j * MM * CC + (size_t)row * CC))[c4];
      a.x += b2f(q.x); a.y += b2f(q.y); a.z += b2f(q.z); a.w += b2f(q.w);
    }
    xr[c4] = a;
    v[i] = a;
    s += a.x + a.y + a.z + a.w;
    sq += a.x * a.x + a.y * a.y + a.z * a.z + a.w * a.w;
  }
#pragma unroll
  for (int m = 1; m < 64; m <<= 1) { s += __shfl_xor(s, m, 64); sq += __shfl_xor(sq, m, 64); }
  const float mu = s * (1.f / 768.f);
  const float rstd = rsqrtf(sq * (1.f / 768.f) - mu * mu + 1e-5f);
  ushort4* orow = (ushort4*)(o + (size_t)row * CC);
#pragma unroll
  for (int i = 0; i < 3; ++i) {
    const int c4 = lane + i * 64;
    const float4 gg = ((const float4*)gamma)[c4];
    const float4 bb = ((const float4*)beta)[c4];
    ushort4 w;
    w.x = f2b((v[i].x - mu) * rstd * gg.x + bb.x);
    w.y = f2b((v[i].y - mu) * rstd * gg.y + bb.y);
    w.z = f2b((v[i].z - mu) * rstd * gg.z + bb.z);
    w.w = f2b((v[i].w - mu) * rstd * gg.w + bb.w);
    orow[c4] = w;
  }
}

// ------- all-weights transpose+convert (6 layers x 4 matrices, one launch) -------
__global__ __launch_bounds__(256) void tca_k(const float* __restrict__ Wq,
                                             const float* __restrict__ Wp,
                                             const float* __restrict__ W1p,
                                             const float* __restrict__ W2p,
                                             uint16_t* __restrict__ dq,
                                             uint16_t* __restrict__ dp,
                                             uint16_t* __restrict__ d1,
                                             uint16_t* __restrict__ d2) {
  __shared__ float tile[32][33];
  const int b = blockIdx.x;
  const int l = b / 6912;
  int r = b - l * 6912;
  const float* src; uint16_t* dst; int K, N, kt, nt;
  if (r < 1728) {
    K = CC; N = 3 * CC;
    src = Wq + (size_t)l * CC * 3 * CC; dst = dq + (size_t)l * CC * 3 * CC;
    kt = r / 72; nt = r % 72;
  } else if (r < 2304) {
    r -= 1728; K = CC; N = CC;
    src = Wp + (size_t)l * CC * CC; dst = dp + (size_t)l * CC * CC;
    kt = r / 24; nt = r % 24;
  } else if (r < 4608) {
    r -= 2304; K = CC; N = DFF;
    src = W1p + (size_t)l * CC * DFF; dst = d1 + (size_t)l * CC * DFF;
    kt = r / 96; nt = r % 96;
  } else {
    r -= 4608; K = DFF; N = CC;
    src = W2p + (size_t)l * DFF * CC; dst = d2 + (size_t)l * DFF * CC;
    kt = r / 24; nt = r % 24;
  }
  const int tx = threadIdx.x & 31, ty = threadIdx.x >> 5;
  const int kb = kt * 32, nb = nt * 32;
#pragma unroll
  for (int i = 0; i < 32; i += 8)
    tile[ty + i][tx] = src[(size_t)(kb + ty + i) * N + nb + tx];
  __syncthreads();
#pragma unroll
  for (int i = 0; i < 32; i += 8)
    dst[(size_t)(nb + ty + i) * K + kb + tx] = f2b(tile[tx][ty + i]);
}

// ---------------- 128x128 GEMM (m97 structure, 16KB LDS, multi-block TLP) ----------------
// split-K via gridDim.z / blockIdx.z.
// EPI: 1 = f32 store; 2 = bias+GELU -> bf16; 5 = qkv split; 8 = bf16 partials (+bias kp0)
template <int EPI>
__global__ __launch_bounds__(256) void gemm_k(const uint16_t* __restrict__ A,
                                              const uint16_t* __restrict__ Bt,
                                              int N, int K,
                                              const float* __restrict__ bias,
                                              uint16_t* __restrict__ outb,
                                              float* __restrict__ outf) {
  __shared__ __align__(16) uint16_t As[128 * 32];
  __shared__ __align__(16) uint16_t Bs[128 * 32];
  const int lane = threadIdx.x & 63, wid = threadIdx.x >> 6;
  const int wm = wid >> 1, wn = wid & 1;
  const int bm = blockIdx.x * 128, bn = blockIdx.y * 128;
  const int kp = blockIdx.z;
  const int Ksub = K / (int)gridDim.z;
  const int k0b = kp * Ksub;
  const int rsub = lane >> 2, csub = (lane & 3) * 8;
  f32x4 acc[4][4] = {};
  for (int k0 = k0b; k0 < k0b + Ksub; k0 += 32) {
#pragma unroll
    for (int q = 0; q < 2; ++q) {
      const int ch = wid * 2 + q;
      gld16(A + (size_t)(bm + ch * 16 + rsub) * K + k0 + csub, &As[ch * 512]);
      gld16(Bt + (size_t)(bn + ch * 16 + rsub) * K + k0 + csub, &Bs[ch * 512]);
    }
    __syncthreads();
    bf16x8 a[4], b[4];
#pragma unroll
    for (int i = 0; i < 4; ++i) {
      a[i] = *(const bf16x8*)&As[(wm * 64 + i * 16 + (lane & 15)) * 32 + (lane >> 4) * 8];
      b[i] = *(const bf16x8*)&Bs[(wn * 64 + i * 16 + (lane & 15)) * 32 + (lane >> 4) * 8];
    }
#pragma unroll
    for (int i = 0; i < 4; ++i)
#pragma unroll
      for (int j = 0; j < 4; ++j)
        acc[i][j] = mfma16(a[i], b[j], acc[i][j]);
    __syncthreads();
  }
#pragma unroll
  for (int i = 0; i < 4; ++i) {
    const int m0 = bm + wm * 64 + i * 16 + ((lane >> 4) << 2);
#pragma unroll
    for (int j = 0; j < 4; ++j) {
      const int n = bn + wn * 64 + j * 16 + (lane & 15);
      if constexpr (EPI == 5) {
        const int sec = n / CC;
        const int rn = n - sec * CC;
        const int hh = rn >> 6, d = rn & 63;
        const int b = m0 >> 10, t0 = m0 & 1023;
        if (sec == 2) {
          ushort4 w;
          w.x = f2b(acc[i][j][0]); w.y = f2b(acc[i][j][1]);
          w.z = f2b(acc[i][j][2]); w.w = f2b(acc[i][j][3]);
          *(ushort4*)(outb + 2 * QKREG + ((size_t)(b * HH + hh) * 64 + d) * TT + t0) = w;
        } else {
          uint16_t* dst = outb + (size_t)sec * QKREG + ((size_t)(b * HH + hh) * TT + t0) * 64 + d;
#pragma unroll
          for (int rr = 0; rr < 4; ++rr) dst[(size_t)rr * 64] = f2b(acc[i][j][rr]);
        }
      } else if constexpr (EPI == 8) {
        uint16_t* pdst = outb + (size_t)kp * ((size_t)MM * N);
        const float bb = (kp == 0 && bias) ? bias[n] : 0.f;
#pragma unroll
        for (int rr = 0; rr < 4; ++rr)
          pdst[(size_t)(m0 + rr) * N + n] = f2b(acc[i][j][rr] + bb);
      } else {
#pragma unroll
        for (int rr = 0; rr < 4; ++rr) {
          const size_t o = (size_t)(m0 + rr) * N + n;
          const float v = acc[i][j][rr];
          if constexpr (EPI == 1) {
            outf[o] = v;
          } else if constexpr (EPI == 2) {
            float t = v + bias[n];
            t = 0.5f * t * (1.0f + erff(t * 0.70710678118654752f));
            outb[o] = f2b(t);
          }
        }
      }
    }
  }
}

// ---------------- fused causal flash attention ----------------
__global__ __launch_bounds__(256) void attn_k(const uint16_t* __restrict__ qkvh,
                                              uint16_t* __restrict__ ao) {
  __shared__ __align__(16) uint16_t Ks[64 * 64], Vs[64 * 64];
  __shared__ __align__(16) uint16_t Ps[4][16 * 64];
  const int tid = threadIdx.x, lane = tid & 63, wid = tid >> 6;
  const int qt = (TT / 64 - 1) - blockIdx.x / (BB * HH);
  const int bh = blockIdx.x % (BB * HH);
  const uint16_t* qb = qkvh + (size_t)bh * (TT * 64);
  const uint16_t* kb = qkvh + QKREG + (size_t)bh * (TT * 64);
  const uint16_t* vb = qkvh + 2 * QKREG + (size_t)bh * ((size_t)64 * TT);
  const int l15 = lane & 15, lhi = lane >> 4;
  bf16x8 qf[2];
  {
    const uint16_t* qr = qb + (size_t)(qt * 64 + wid * 16 + l15) * 64 + lhi * 8;
    qf[0] = *(const bf16x8*)qr;
    qf[1] = *(const bf16x8*)(qr + 32);
  }
  const int c0 = tid, c1 = tid + 256;
  const int r0 = c0 >> 3, r1 = c1 >> 3;
  const int cb0 = (c0 & 7) * 16, cb1 = (c1 & 7) * 16;
  const int ph0 = r0 * 128 + (cb0 ^ ((r0 & 7) << 4));
  const int ph1 = r1 * 128 + (cb1 ^ ((r1 & 7) << 4));

  uint4 kr0, kr1, vr0, vr1;
  kr0 = *(const uint4*)(kb + (size_t)r0 * 64 + cb0 / 2);
  kr1 = *(const uint4*)(kb + (size_t)r1 * 64 + cb1 / 2);
  vr0 = *(const uint4*)(vb + (size_t)r0 * TT + cb0 / 2);
  vr1 = *(const uint4*)(vb + (size_t)r1 * TT + cb1 / 2);
  *(uint4*)((char*)Ks + ph0) = kr0;
  *(uint4*)((char*)Ks + ph1) = kr1;
  *(uint4*)((char*)Vs + ph0) = vr0;
  *(uint4*)((char*)Vs + ph1) = vr1;
  __syncthreads();

  f32x4 oacc[4] = {};
  float mrun[4] = {-INFINITY, -INFINITY, -INFINITY, -INFINITY};
  float lrun[4] = {0.f, 0.f, 0.f, 0.f};
  char* pb = (char*)Ps[wid];

  for (int j = 0; j <= qt; ++j) {
    const bool more = (j < qt);
    if (more) {
      const int jn = (j + 1) * 64;
      kr0 = *(const uint4*)(kb + (size_t)(jn + r0) * 64 + cb0 / 2);
      kr1 = *(const uint4*)(kb + (size_t)(jn + r1) * 64 + cb1 / 2);
      vr0 = *(const uint4*)(vb + (size_t)r0 * TT + jn + cb0 / 2);
      vr1 = *(const uint4*)(vb + (size_t)r1 * TT + jn + cb1 / 2);
    }
    f32x4 s4[4] = {};
    __builtin_amdgcn_s_setprio(1);
#pragma unroll
    for (int kk = 0; kk < 2; ++kk) {
      const int cbyte = kk * 64 + lhi * 16;
#pragma unroll
      for (int nt = 0; nt < 4; ++nt) {
        const int krow = nt * 16 + l15;
        const bf16x8 kf = *(const bf16x8*)((char*)Ks + krow * 128 + (cbyte ^ ((krow & 7) << 4)));
        s4[nt] = mfma16(qf[kk], kf, s4[nt]);
      }
    }
    __builtin_amdgcn_s_setprio(0);
    const bool diag = (j == qt);
    float alpha[4];
#pragma unroll
    for (int r = 0; r < 4; ++r) {
      const int qg = qt * 64 + wid * 16 + (lhi << 2) + r;
      float mx = -INFINITY;
#pragma unroll
      for (int nt = 0; nt < 4; ++nt) {
        float v = s4[nt][r] * 0.125f;
        if (diag && (j * 64 + nt * 16 + l15) > qg) v = -INFINITY;
        s4[nt][r] = v;
        mx = fmaxf(mx, v);
      }
#pragma unroll
      for (int m = 1; m < 16; m <<= 1) mx = fmaxf(mx, __shfl_xor(mx, m, 16));
      const float mnew = fmaxf(mrun[r], mx);
      alpha[r] = __expf(mrun[r] - mnew);
      float ps = 0.f;
#pragma unroll
      for (int nt = 0; nt < 4; ++nt) {
        const float pp = __expf(s4[nt][r] - mnew);
        s4[nt][r] = pp;
        ps += pp;
      }
#pragma unroll
      for (int m = 1; m < 16; m <<= 1) ps += __shfl_xor(ps, m, 16);
      lrun[r] = lrun[r] * alpha[r] + ps;
      mrun[r] = mnew;
    }
#pragma unroll
    for (int dt = 0; dt < 4; ++dt)
#pragma unroll
      for (int r = 0; r < 4; ++r) oacc[dt][r] *= alpha[r];
#pragma unroll
    for (int r = 0; r < 4; ++r) {
      const int prow = (lhi << 2) + r;
      const int swp = (prow & 7) << 4;
#pragma unroll
      for (int nt = 0; nt < 4; ++nt) {
        const int cb = (nt * 16 + l15) * 2;
        *(uint16_t*)(pb + prow * 128 + (cb ^ swp)) = f2b(s4[nt][r]);
      }
    }
    __builtin_amdgcn_s_setprio(1);
#pragma unroll
    for (int kk = 0; kk < 2; ++kk) {
      const int cbyte = kk * 64 + lhi * 16;
      const bf16x8 pf = *(const bf16x8*)(pb + l15 * 128 + (cbyte ^ ((l15 & 7) << 4)));
#pragma unroll
      for (int dt = 0; dt < 4; ++dt) {
        const int vrow = dt * 16 + l15;
        const bf16x8 vf = *(const bf16x8*)((char*)Vs + vrow * 128 + (cbyte ^ ((vrow & 7) << 4)));
        oacc[dt] = mfma16(pf, vf, oacc[dt]);
      }
    }
    __builtin_amdgcn_s_setprio(0);
    __syncthreads();
    if (more) {
      *(uint4*)((char*)Ks + ph0) = kr0;
      *(uint4*)((char*)Ks + ph1) = kr1;
      *(uint4*)((char*)Vs + ph0) = vr0;
      *(uint4*)((char*)Vs + ph1) = vr1;
    }
    __syncthreads();
  }
#pragma unroll
  for (int dt = 0; dt < 4; ++dt) {
#pragma unroll
    for (int r = 0; r < 4; ++r) {
      const int q = qt * 64 + wid * 16 + (lhi << 2) + r;
      const float v = oacc[dt][r] / lrun[r];
      ao[(size_t)((bh / HH) * TT + q) * CC + (bh % HH) * HDIM + dt * 16 + l15] = f2b(v);
    }
  }
}

extern "C" void kernel_launch(void* const* d_in, const int* in_sizes, int n_in,
                              void* d_out, int out_size, void* d_ws, size_t ws_size,
                              hipStream_t stream) {
  (void)in_sizes; (void)n_in; (void)out_size;
  const int*   idx  = (const int*)d_in[0];
  const float* tok  = (const float*)d_in[1];
  const float* pos  = (const float*)d_in[2];
  const float* Wqkv = (const float*)d_in[3];
  const float* Wpro = (const float*)d_in[4];
  const float* W1   = (const float*)d_in[5];
  const float* b1   = (const float*)d_in[6];
  const float* W2   = (const float*)d_in[7];
  const float* b2   = (const float*)d_in[8];
  const float* g1   = (const float*)d_in[9];
  const float* be1  = (const float*)d_in[10];
  const float* g2   = (const float*)d_in[11];
  const float* be2  = (const float*)d_in[12];
  const float* gf   = (const float*)d_in[13];
  const float* bfb  = (const float*)d_in[14];
  float* out = (float*)d_out;

  const size_t QS = (size_t)CC * 3 * CC;
  const size_t PS = (size_t)CC * CC;
  const size_t S1 = (size_t)CC * DFF;
  const size_t S2 = (size_t)DFF * CC;

  char* p = (char*)d_ws;
  float* x = (float*)p;            p += (size_t)MM * CC * 4;
  uint16_t* act = (uint16_t*)p;    p += (size_t)MM * CC * 2;
  uint16_t* big = (uint16_t*)p;    p += (size_t)MM * DFF * 2;
  uint16_t* tokb = (uint16_t*)p;   p += (size_t)VV * CC * 2;
  uint16_t* partb = (uint16_t*)p;  p += (size_t)4 * MM * CC * 2;   // bf16 split-K partials
  char* pbase = p;
  uint16_t* wqA = (uint16_t*)p;    p += QS * LNUM * 2;
  uint16_t* wpA = (uint16_t*)p;    p += PS * LNUM * 2;
  uint16_t* w1A = (uint16_t*)p;    p += S1 * LNUM * 2;
  uint16_t* w2A = (uint16_t*)p;    p += S2 * LNUM * 2;
  const bool roomy2 = ws_size >= (size_t)(p - (char*)d_ws);
  if (!roomy2) {
    p = pbase;
    wqA = (uint16_t*)p; p += QS * 2;
    wpA = (uint16_t*)p; p += PS * 2;
    w1A = (uint16_t*)p; p += S1 * 2;
    w2A = (uint16_t*)p; p += S2 * 2;
  }

  cvt4_k<<<dim3((VV * CC / 4 + 255) / 256), 256, 0, stream>>>(tok, tokb, VV * CC / 4);
  embed_k<<<dim3(MM * (CC / 4) / 256), 256, 0, stream>>>(idx, tok, pos, x);
  ln_k<<<dim3(MM / 4), 256, 0, stream>>>(x, g1, be1, act);
  if (roomy2)
    tca_k<<<dim3(LNUM * 6912), 256, 0, stream>>>(Wqkv, Wpro, W1, W2, wqA, wpA, w1A, w2A);

  for (int l = 0; l < LNUM; ++l) {
    if (!roomy2)
      tca_k<<<dim3(6912), 256, 0, stream>>>(Wqkv + (size_t)l * QS, Wpro + (size_t)l * PS,
                                            W1 + (size_t)l * S1, W2 + (size_t)l * S2,
                                            wqA, wpA, w1A, w2A);
    const size_t lw = roomy2 ? (size_t)l : 0;
    // QKV: 64x18 = 1152 blocks (4.5/CU)
    gemm_k<5><<<dim3(MM / 128, 3 * CC / 128, 1), 256, 0, stream>>>(
        act, wqA + lw * QS, 3 * CC, CC, nullptr, big, nullptr);
    attn_k<<<dim3((TT / 64) * BB * HH), 256, 0, stream>>>(big, act);
    // proj: split-K2 bf16 partials -> 64x6x2 = 768 blocks (3/CU)
    gemm_k<8><<<dim3(MM / 128, CC / 128, 2), 256, 0, stream>>>(
        act, wpA + lw * PS, CC, CC, nullptr, partb, nullptr);
    lnrb_k<2><<<dim3(MM / 4), 256, 0, stream>>>(x, partb,
                                                g2 + (size_t)l * CC, be2 + (size_t)l * CC, act);
    // W1 + GELU: 64x24 = 1536 blocks (6/CU)
    gemm_k<2><<<dim3(MM / 128, DFF / 128, 1), 256, 0, stream>>>(
        act, w1A + lw * S1, DFF, CC, b1 + (size_t)l * DFF, big, nullptr);
    // W2: split-K4 bf16 partials -> 64x6x4 = 1536 blocks (6/CU)
    const float* ng = (l + 1 < LNUM) ? g1 + (size_t)(l + 1) * CC : gf;
    const float* nb = (l + 1 < LNUM) ? be1 + (size_t)(l + 1) * CC : bfb;
    gemm_k<8><<<dim3(MM / 128, CC / 128, 4), 256, 0, stream>>>(
        big, w2A + lw * S2, CC, DFF, b2 + (size_t)l * CC, partb, nullptr);
    lnrb_k<4><<<dim3(MM / 4), 256, 0, stream>>>(x, partb, ng, nb, act);
  }
  gemm_k<1><<<dim3(MM / 128, VV / 128, 1), 256, 0, stream>>>(
      act, tokb, VV, CC, nullptr, nullptr, out);
}

// Round 11
// 1684.109 us; speedup vs baseline: 1.0572x; 1.0572x over previous
//
#include <hip/hip_runtime.h>
#include <hip/hip_bf16.h>
#include <stdint.h>

#define LNUM 6
#define BB 8
#define TT 1024
#define CC 768
#define HH 12
#define HDIM 64
#define DFF 3072
#define VV 512
#define MM (BB*TT)
#define QKREG ((size_t)BB*HH*TT*64)

typedef __bf16 bf16x8 __attribute__((ext_vector_type(8)));
typedef float f32x4 __attribute__((ext_vector_type(4)));

__device__ __forceinline__ uint16_t f2b(float f) {
  uint32_t u = __float_as_uint(f);
  u += 0x7FFFu + ((u >> 16) & 1u);
  return (uint16_t)(u >> 16);
}

__device__ __forceinline__ float b2f(uint16_t u) {
  return __uint_as_float((uint32_t)u << 16);
}

__device__ __forceinline__ void gld16(const uint16_t* g, uint16_t* l) {
  __builtin_amdgcn_global_load_lds(
      (const __attribute__((address_space(1))) uint32_t*)g,
      (__attribute__((address_space(3))) uint32_t*)l, 16, 0, 0);
}

__device__ __forceinline__ f32x4 mfma16(bf16x8 a, bf16x8 b, f32x4 c) {
  return __builtin_amdgcn_mfma_f32_16x16x32_bf16(a, b, c, 0, 0, 0);
}

// ---------------- convert f32 -> bf16 ----------------
__global__ __launch_bounds__(256) void cvt4_k(const float* __restrict__ in,
                                              uint16_t* __restrict__ out, int n4) {
  const int gid = blockIdx.x * 256 + threadIdx.x;
  if (gid >= n4) return;
  const float4 v = ((const float4*)in)[gid];
  ushort4 w; w.x = f2b(v.x); w.y = f2b(v.y); w.z = f2b(v.z); w.w = f2b(v.w);
  ((ushort4*)out)[gid] = w;
}

// ---------------- embedding ----------------
__global__ __launch_bounds__(256) void embed_k(const int* __restrict__ idx,
                                               const float* __restrict__ tok,
                                               const float* __restrict__ pos,
                                               float* __restrict__ x) {
  const int gid = blockIdx.x * 256 + threadIdx.x;
  const int row = gid / (CC / 4), c4 = gid % (CC / 4);
  const int t = row & (TT - 1);
  const int tkn = idx[row];
  const float4 a = ((const float4*)(tok + (size_t)tkn * CC))[c4];
  const float4 q = ((const float4*)(pos + (size_t)t * CC))[c4];
  ((float4*)(x + (size_t)row * CC))[c4] =
      make_float4(a.x + q.x, a.y + q.y, a.z + q.z, a.w + q.w);
}

// ---------------- layernorm: fp32 in -> bf16 out ----------------
__global__ __launch_bounds__(256) void ln_k(const float* __restrict__ x,
                                            const float* __restrict__ gamma,
                                            const float* __restrict__ beta,
                                            uint16_t* __restrict__ o) {
  const int lane = threadIdx.x & 63, wid = threadIdx.x >> 6;
  const int row = blockIdx.x * 4 + wid;
  const float4* xr = (const float4*)(x + (size_t)row * CC);
  float4 v[3]; float s = 0.f, sq = 0.f;
#pragma unroll
  for (int i = 0; i < 3; ++i) {
    v[i] = xr[lane + i * 64];
    s += v[i].x + v[i].y + v[i].z + v[i].w;
    sq += v[i].x * v[i].x + v[i].y * v[i].y + v[i].z * v[i].z + v[i].w * v[i].w;
  }
#pragma unroll
  for (int m = 1; m < 64; m <<= 1) { s += __shfl_xor(s, m, 64); sq += __shfl_xor(sq, m, 64); }
  const float mu = s * (1.f / 768.f);
  const float rstd = rsqrtf(sq * (1.f / 768.f) - mu * mu + 1e-5f);
  ushort4* orow = (ushort4*)(o + (size_t)row * CC);
#pragma unroll
  for (int i = 0; i < 3; ++i) {
    const int c4 = lane + i * 64;
    const float4 gg = ((const float4*)gamma)[c4];
    const float4 bb = ((const float4*)beta)[c4];
    ushort4 w;
    w.x = f2b((v[i].x - mu) * rstd * gg.x + bb.x);
    w.y = f2b((v[i].y - mu) * rstd * gg.y + bb.y);
    w.z = f2b((v[i].z - mu) * rstd * gg.z + bb.z);
    w.w = f2b((v[i].w - mu) * rstd * gg.w + bb.w);
    orow[c4] = w;
  }
}

// ------- layernorm + NP bf16-partial reduce: x += sum(p_j); o = LN(x) -------
template <int NP>
__global__ __launch_bounds__(256) void lnrb_k(float* __restrict__ x,
                                              const uint16_t* __restrict__ pp,
                                              const float* __restrict__ gamma,
                                              const float* __restrict__ beta,
                                              uint16_t* __restrict__ o) {
  const int lane = threadIdx.x & 63, wid = threadIdx.x >> 6;
  const int row = blockIdx.x * 4 + wid;
  float4* xr = (float4*)(x + (size_t)row * CC);
  float4 v[3]; float s = 0.f, sq = 0.f;
#pragma unroll
  for (int i = 0; i < 3; ++i) {
    const int c4 = lane + i * 64;
    float4 a = xr[c4];
#pragma unroll
    for (int j = 0; j < NP; ++j) {
      const ushort4 q =
          ((const ushort4*)(pp + (size_t)j * MM * CC + (size_t)row * CC))[c4];
      a.x += b2f(q.x); a.y += b2f(q.y); a.z += b2f(q.z); a.w += b2f(q.w);
    }
    xr[c4] = a;
    v[i] = a;
    s += a.x + a.y + a.z + a.w;
    sq += a.x * a.x + a.y * a.y + a.z * a.z + a.w * a.w;
  }
#pragma unroll
  for (int m = 1; m < 64; m <<= 1) { s += __shfl_xor(s, m, 64); sq += __shfl_xor(sq, m, 64); }
  const float mu = s * (1.f / 768.f);
  const float rstd = rsqrtf(sq * (1.f / 768.f) - mu * mu + 1e-5f);
  ushort4* orow = (ushort4*)(o + (size_t)row * CC);
#pragma unroll
  for (int i = 0; i < 3; ++i) {
    const int c4 = lane + i * 64;
    const float4 gg = ((const float4*)gamma)[c4];
    const float4 bb = ((const float4*)beta)[c4];
    ushort4 w;
    w.x = f2b((v[i].x - mu) * rstd * gg.x + bb.x);
    w.y = f2b((v[i].y - mu) * rstd * gg.y + bb.y);
    w.z = f2b((v[i].z - mu) * rstd * gg.z + bb.z);
    w.w = f2b((v[i].w - mu) * rstd * gg.w + bb.w);
    orow[c4] = w;
  }
}

// ------- all-weights transpose+convert (6 layers x 4 matrices, one launch) -------
__global__ __launch_bounds__(256) void tca_k(const float* __restrict__ Wq,
                                             const float* __restrict__ Wp,
                                             const float* __restrict__ W1p,
                                             const float* __restrict__ W2p,
                                             uint16_t* __restrict__ dq,
                                             uint16_t* __restrict__ dp,
                                             uint16_t* __restrict__ d1,
                                             uint16_t* __restrict__ d2) {
  __shared__ float tile[32][33];
  const int b = blockIdx.x;
  const int l = b / 6912;
  int r = b - l * 6912;
  const float* src; uint16_t* dst; int K, N, kt, nt;
  if (r < 1728) {
    K = CC; N = 3 * CC;
    src = Wq + (size_t)l * CC * 3 * CC; dst = dq + (size_t)l * CC * 3 * CC;
    kt = r / 72; nt = r % 72;
  } else if (r < 2304) {
    r -= 1728; K = CC; N = CC;
    src = Wp + (size_t)l * CC * CC; dst = dp + (size_t)l * CC * CC;
    kt = r / 24; nt = r % 24;
  } else if (r < 4608) {
    r -= 2304; K = CC; N = DFF;
    src = W1p + (size_t)l * CC * DFF; dst = d1 + (size_t)l * CC * DFF;
    kt = r / 96; nt = r % 96;
  } else {
    r -= 4608; K = DFF; N = CC;
    src = W2p + (size_t)l * DFF * CC; dst = d2 + (size_t)l * DFF * CC;
    kt = r / 24; nt = r % 24;
  }
  const int tx = threadIdx.x & 31, ty = threadIdx.x >> 5;
  const int kb = kt * 32, nb = nt * 32;
#pragma unroll
  for (int i = 0; i < 32; i += 8)
    tile[ty + i][tx] = src[(size_t)(kb + ty + i) * N + nb + tx];
  __syncthreads();
#pragma unroll
  for (int i = 0; i < 32; i += 8)
    dst[(size_t)(nb + ty + i) * K + kb + tx] = f2b(tile[tx][ty + i]);
}

// ---------------- 128x128 GEMM (m97 structure + chunk-swizzled LDS) ----------------
// LDS tile rows are 64B (32 bf16) = 4 chunks of 16B. Without swizzle the
// fragment read (16 lanes, stride 64B) is an 8-way bank conflict. Swizzle:
// LDS(row, pos) holds global chunk pos ^ ((row>>1)&3); applied on the
// pre-swizzled global SOURCE (gld16 dest stays linear, rule 21) and on the
// read position. Post-swizzle the 16-lane group covers 8 distinct bank
// starts -> 2-way (free, m136).
// split-K via gridDim.z / blockIdx.z.
// EPI: 1 = f32 store; 2 = bias+GELU -> bf16; 5 = qkv split; 8 = bf16 partials (+bias kp0)
template <int EPI>
__global__ __launch_bounds__(256) void gemm_k(const uint16_t* __restrict__ A,
                                              const uint16_t* __restrict__ Bt,
                                              int N, int K,
                                              const float* __restrict__ bias,
                                              uint16_t* __restrict__ outb,
                                              float* __restrict__ outf) {
  __shared__ __align__(16) uint16_t As[128 * 32];
  __shared__ __align__(16) uint16_t Bs[128 * 32];
  const int lane = threadIdx.x & 63, wid = threadIdx.x >> 6;
  const int wm = wid >> 1, wn = wid & 1;
  const int bm = blockIdx.x * 128, bn = blockIdx.y * 128;
  const int kp = blockIdx.z;
  const int Ksub = K / (int)gridDim.z;
  const int k0b = kp * Ksub;
  const int rsub = lane >> 2;
  // source chunk = (dest chunk lane&3) ^ f(row), f(r)=(r>>1)&3, row=ch*16+rsub
  const int csub = (((lane & 3) ^ ((lane >> 3) & 3))) * 8;
  // read position = lhi ^ f(row), row = ...16*i + l15 -> f = (l15>>1)&3
  const int cof = (((lane >> 4) ^ ((lane >> 1) & 3))) * 8;
  const int l15 = lane & 15;
  f32x4 acc[4][4] = {};
  for (int k0 = k0b; k0 < k0b + Ksub; k0 += 32) {
#pragma unroll
    for (int q = 0; q < 2; ++q) {
      const int ch = wid * 2 + q;
      gld16(A + (size_t)(bm + ch * 16 + rsub) * K + k0 + csub, &As[ch * 512]);
      gld16(Bt + (size_t)(bn + ch * 16 + rsub) * K + k0 + csub, &Bs[ch * 512]);
    }
    __syncthreads();
    bf16x8 a[4], b[4];
#pragma unroll
    for (int i = 0; i < 4; ++i) {
      a[i] = *(const bf16x8*)&As[(wm * 64 + i * 16 + l15) * 32 + cof];
      b[i] = *(const bf16x8*)&Bs[(wn * 64 + i * 16 + l15) * 32 + cof];
    }
#pragma unroll
    for (int i = 0; i < 4; ++i)
#pragma unroll
      for (int j = 0; j < 4; ++j)
        acc[i][j] = mfma16(a[i], b[j], acc[i][j]);
    __syncthreads();
  }
#pragma unroll
  for (int i = 0; i < 4; ++i) {
    const int m0 = bm + wm * 64 + i * 16 + ((lane >> 4) << 2);
#pragma unroll
    for (int j = 0; j < 4; ++j) {
      const int n = bn + wn * 64 + j * 16 + l15;
      if constexpr (EPI == 5) {
        const int sec = n / CC;
        const int rn = n - sec * CC;
        const int hh = rn >> 6, d = rn & 63;
        const int b = m0 >> 10, t0 = m0 & 1023;
        if (sec == 2) {
          ushort4 w;
          w.x = f2b(acc[i][j][0]); w.y = f2b(acc[i][j][1]);
          w.z = f2b(acc[i][j][2]); w.w = f2b(acc[i][j][3]);
          *(ushort4*)(outb + 2 * QKREG + ((size_t)(b * HH + hh) * 64 + d) * TT + t0) = w;
        } else {
          uint16_t* dst = outb + (size_t)sec * QKREG + ((size_t)(b * HH + hh) * TT + t0) * 64 + d;
#pragma unroll
          for (int rr = 0; rr < 4; ++rr) dst[(size_t)rr * 64] = f2b(acc[i][j][rr]);
        }
      } else if constexpr (EPI == 8) {
        uint16_t* pdst = outb + (size_t)kp * ((size_t)MM * N);
        const float bb = (kp == 0 && bias) ? bias[n] : 0.f;
#pragma unroll
        for (int rr = 0; rr < 4; ++rr)
          pdst[(size_t)(m0 + rr) * N + n] = f2b(acc[i][j][rr] + bb);
      } else {
#pragma unroll
        for (int rr = 0; rr < 4; ++rr) {
          const size_t o = (size_t)(m0 + rr) * N + n;
          const float v = acc[i][j][rr];
          if constexpr (EPI == 1) {
            outf[o] = v;
          } else if constexpr (EPI == 2) {
            float t = v + bias[n];
            t = 0.5f * t * (1.0f + erff(t * 0.70710678118654752f));
            outb[o] = f2b(t);
          }
        }
      }
    }
  }
}

// ---------------- fused causal flash attention ----------------
__global__ __launch_bounds__(256) void attn_k(const uint16_t* __restrict__ qkvh,
                                              uint16_t* __restrict__ ao) {
  __shared__ __align__(16) uint16_t Ks[64 * 64], Vs[64 * 64];
  __shared__ __align__(16) uint16_t Ps[4][16 * 64];
  const int tid = threadIdx.x, lane = tid & 63, wid = tid >> 6;
  const int qt = (TT / 64 - 1) - blockIdx.x / (BB * HH);
  const int bh = blockIdx.x % (BB * HH);
  const uint16_t* qb = qkvh + (size_t)bh * (TT * 64);
  const uint16_t* kb = qkvh + QKREG + (size_t)bh * (TT * 64);
  const uint16_t* vb = qkvh + 2 * QKREG + (size_t)bh * ((size_t)64 * TT);
  const int l15 = lane & 15, lhi = lane >> 4;
  bf16x8 qf[2];
  {
    const uint16_t* qr = qb + (size_t)(qt * 64 + wid * 16 + l15) * 64 + lhi * 8;
    qf[0] = *(const bf16x8*)qr;
    qf[1] = *(const bf16x8*)(qr + 32);
  }
  const int c0 = tid, c1 = tid + 256;
  const int r0 = c0 >> 3, r1 = c1 >> 3;
  const int cb0 = (c0 & 7) * 16, cb1 = (c1 & 7) * 16;
  const int ph0 = r0 * 128 + (cb0 ^ ((r0 & 7) << 4));
  const int ph1 = r1 * 128 + (cb1 ^ ((r1 & 7) << 4));

  uint4 kr0, kr1, vr0, vr1;
  kr0 = *(const uint4*)(kb + (size_t)r0 * 64 + cb0 / 2);
  kr1 = *(const uint4*)(kb + (size_t)r1 * 64 + cb1 / 2);
  vr0 = *(const uint4*)(vb + (size_t)r0 * TT + cb0 / 2);
  vr1 = *(const uint4*)(vb + (size_t)r1 * TT + cb1 / 2);
  *(uint4*)((char*)Ks + ph0) = kr0;
  *(uint4*)((char*)Ks + ph1) = kr1;
  *(uint4*)((char*)Vs + ph0) = vr0;
  *(uint4*)((char*)Vs + ph1) = vr1;
  __syncthreads();

  f32x4 oacc[4] = {};
  float mrun[4] = {-INFINITY, -INFINITY, -INFINITY, -INFINITY};
  float lrun[4] = {0.f, 0.f, 0.f, 0.f};
  char* pb = (char*)Ps[wid];

  for (int j = 0; j <= qt; ++j) {
    const bool more = (j < qt);
    if (more) {
      const int jn = (j + 1) * 64;
      kr0 = *(const uint4*)(kb + (size_t)(jn + r0) * 64 + cb0 / 2);
      kr1 = *(const uint4*)(kb + (size_t)(jn + r1) * 64 + cb1 / 2);
      vr0 = *(const uint4*)(vb + (size_t)r0 * TT + jn + cb0 / 2);
      vr1 = *(const uint4*)(vb + (size_t)r1 * TT + jn + cb1 / 2);
    }
    f32x4 s4[4] = {};
    __builtin_amdgcn_s_setprio(1);
#pragma unroll
    for (int kk = 0; kk < 2; ++kk) {
      const int cbyte = kk * 64 + lhi * 16;
#pragma unroll
      for (int nt = 0; nt < 4; ++nt) {
        const int krow = nt * 16 + l15;
        const bf16x8 kf = *(const bf16x8*)((char*)Ks + krow * 128 + (cbyte ^ ((krow & 7) << 4)));
        s4[nt] = mfma16(qf[kk], kf, s4[nt]);
      }
    }
    __builtin_amdgcn_s_setprio(0);
    const bool diag = (j == qt);
    float alpha[4];
#pragma unroll
    for (int r = 0; r < 4; ++r) {
      const int qg = qt * 64 + wid * 16 + (lhi << 2) + r;
      float mx = -INFINITY;
#pragma unroll
      for (int nt = 0; nt < 4; ++nt) {
        float v = s4[nt][r] * 0.125f;
        if (diag && (j * 64 + nt * 16 + l15) > qg) v = -INFINITY;
        s4[nt][r] = v;
        mx = fmaxf(mx, v);
      }
#pragma unroll
      for (int m = 1; m < 16; m <<= 1) mx = fmaxf(mx, __shfl_xor(mx, m, 16));
      const float mnew = fmaxf(mrun[r], mx);
      alpha[r] = __expf(mrun[r] - mnew);
      float ps = 0.f;
#pragma unroll
      for (int nt = 0; nt < 4; ++nt) {
        const float pp = __expf(s4[nt][r] - mnew);
        s4[nt][r] = pp;
        ps += pp;
      }
#pragma unroll
      for (int m = 1; m < 16; m <<= 1) ps += __shfl_xor(ps, m, 16);
      lrun[r] = lrun[r] * alpha[r] + ps;
      mrun[r] = mnew;
    }
#pragma unroll
    for (int dt = 0; dt < 4; ++dt)
#pragma unroll
      for (int r = 0; r < 4; ++r) oacc[dt][r] *= alpha[r];
#pragma unroll
    for (int r = 0; r < 4; ++r) {
      const int prow = (lhi << 2) + r;
      const int swp = (prow & 7) << 4;
#pragma unroll
      for (int nt = 0; nt < 4; ++nt) {
        const int cb = (nt * 16 + l15) * 2;
        *(uint16_t*)(pb + prow * 128 + (cb ^ swp)) = f2b(s4[nt][r]);
      }
    }
    __builtin_amdgcn_s_setprio(1);
#pragma unroll
    for (int kk = 0; kk < 2; ++kk) {
      const int cbyte = kk * 64 + lhi * 16;
      const bf16x8 pf = *(const bf16x8*)(pb + l15 * 128 + (cbyte ^ ((l15 & 7) << 4)));
#pragma unroll
      for (int dt = 0; dt < 4; ++dt) {
        const int vrow = dt * 16 + l15;
        const bf16x8 vf = *(const bf16x8*)((char*)Vs + vrow * 128 + (cbyte ^ ((vrow & 7) << 4)));
        oacc[dt] = mfma16(pf, vf, oacc[dt]);
      }
    }
    __builtin_amdgcn_s_setprio(0);
    __syncthreads();
    if (more) {
      *(uint4*)((char*)Ks + ph0) = kr0;
      *(uint4*)((char*)Ks + ph1) = kr1;
      *(uint4*)((char*)Vs + ph0) = vr0;
      *(uint4*)((char*)Vs + ph1) = vr1;
    }
    __syncthreads();
  }
#pragma unroll
  for (int dt = 0; dt < 4; ++dt) {
#pragma unroll
    for (int r = 0; r < 4; ++r) {
      const int q = qt * 64 + wid * 16 + (lhi << 2) + r;
      const float v = oacc[dt][r] / lrun[r];
      ao[(size_t)((bh / HH) * TT + q) * CC + (bh % HH) * HDIM + dt * 16 + l15] = f2b(v);
    }
  }
}

extern "C" void kernel_launch(void* const* d_in, const int* in_sizes, int n_in,
                              void* d_out, int out_size, void* d_ws, size_t ws_size,
                              hipStream_t stream) {
  (void)in_sizes; (void)n_in; (void)out_size;
  const int*   idx  = (const int*)d_in[0];
  const float* tok  = (const float*)d_in[1];
  const float* pos  = (const float*)d_in[2];
  const float* Wqkv = (const float*)d_in[3];
  const float* Wpro = (const float*)d_in[4];
  const float* W1   = (const float*)d_in[5];
  const float* b1   = (const float*)d_in[6];
  const float* W2   = (const float*)d_in[7];
  const float* b2   = (const float*)d_in[8];
  const float* g1   = (const float*)d_in[9];
  const float* be1  = (const float*)d_in[10];
  const float* g2   = (const float*)d_in[11];
  const float* be2  = (const float*)d_in[12];
  const float* gf   = (const float*)d_in[13];
  const float* bfb  = (const float*)d_in[14];
  float* out = (float*)d_out;

  const size_t QS = (size_t)CC * 3 * CC;
  const size_t PS = (size_t)CC * CC;
  const size_t S1 = (size_t)CC * DFF;
  const size_t S2 = (size_t)DFF * CC;

  char* p = (char*)d_ws;
  float* x = (float*)p;            p += (size_t)MM * CC * 4;
  uint16_t* act = (uint16_t*)p;    p += (size_t)MM * CC * 2;
  uint16_t* big = (uint16_t*)p;    p += (size_t)MM * DFF * 2;
  uint16_t* tokb = (uint16_t*)p;   p += (size_t)VV * CC * 2;
  uint16_t* partb = (uint16_t*)p;  p += (size_t)2 * MM * CC * 2;   // bf16 split-K partials
  char* pbase = p;
  uint16_t* wqA = (uint16_t*)p;    p += QS * LNUM * 2;
  uint16_t* wpA = (uint16_t*)p;    p += PS * LNUM * 2;
  uint16_t* w1A = (uint16_t*)p;    p += S1 * LNUM * 2;
  uint16_t* w2A = (uint16_t*)p;    p += S2 * LNUM * 2;
  const bool roomy2 = ws_size >= (size_t)(p - (char*)d_ws);
  if (!roomy2) {
    p = pbase;
    wqA = (uint16_t*)p; p += QS * 2;
    wpA = (uint16_t*)p; p += PS * 2;
    w1A = (uint16_t*)p; p += S1 * 2;
    w2A = (uint16_t*)p; p += S2 * 2;
  }

  cvt4_k<<<dim3((VV * CC / 4 + 255) / 256), 256, 0, stream>>>(tok, tokb, VV * CC / 4);
  embed_k<<<dim3(MM * (CC / 4) / 256), 256, 0, stream>>>(idx, tok, pos, x);
  ln_k<<<dim3(MM / 4), 256, 0, stream>>>(x, g1, be1, act);
  if (roomy2)
    tca_k<<<dim3(LNUM * 6912), 256, 0, stream>>>(Wqkv, Wpro, W1, W2, wqA, wpA, w1A, w2A);

  for (int l = 0; l < LNUM; ++l) {
    if (!roomy2)
      tca_k<<<dim3(6912), 256, 0, stream>>>(Wqkv + (size_t)l * QS, Wpro + (size_t)l * PS,
                                            W1 + (size_t)l * S1, W2 + (size_t)l * S2,
                                            wqA, wpA, w1A, w2A);
    const size_t lw = roomy2 ? (size_t)l : 0;
    // QKV: 64x18 = 1152 blocks (4.5/CU)
    gemm_k<5><<<dim3(MM / 128, 3 * CC / 128, 1), 256, 0, stream>>>(
        act, wqA + lw * QS, 3 * CC, CC, nullptr, big, nullptr);
    attn_k<<<dim3((TT / 64) * BB * HH), 256, 0, stream>>>(big, act);
    // proj: split-K2 bf16 partials -> 64x6x2 = 768 blocks (3/CU)
    gemm_k<8><<<dim3(MM / 128, CC / 128, 2), 256, 0, stream>>>(
        act, wpA + lw * PS, CC, CC, nullptr, partb, nullptr);
    lnrb_k<2><<<dim3(MM / 4), 256, 0, stream>>>(x, partb,
                                                g2 + (size_t)l * CC, be2 + (size_t)l * CC, act);
    // W1 + GELU: 64x24 = 1536 blocks (6/CU)
    gemm_k<2><<<dim3(MM / 128, DFF / 128, 1), 256, 0, stream>>>(
        act, w1A + lw * S1, DFF, CC, b1 + (size_t)l * DFF, big, nullptr);
    // W2: split-K2 bf16 partials -> 64x6x2 = 768 blocks
    const float* ng = (l + 1 < LNUM) ? g1 + (size_t)(l + 1) * CC : gf;
    const float* nb = (l + 1 < LNUM) ? be1 + (size_t)(l + 1) * CC : bfb;
    gemm_k<8><<<dim3(MM / 128, CC / 128, 2), 256, 0, stream>>>(
        big, w2A + lw * S2, CC, DFF, b2 + (size_t)l * CC, partb, nullptr);
    lnrb_k<2><<<dim3(MM / 4), 256, 0, stream>>>(x, partb, ng, nb, act);
  }
  gemm_k<1><<<dim3(MM / 128, VV / 128, 1), 256, 0, stream>>>(
      act, tokb, VV, CC, nullptr, nullptr, out);
}

// Round 12
// 1532.342 us; speedup vs baseline: 1.1619x; 1.0990x over previous
//
#include <hip/hip_runtime.h>
#include <hip/hip_bf16.h>
#include <stdint.h>

#define LNUM 6
#define BB 8
#define TT 1024
#define CC 768
#define HH 12
#define HDIM 64
#define DFF 3072
#define VV 512
#define MM (BB*TT)
#define QKREG ((size_t)BB*HH*TT*64)

typedef __bf16 bf16x8 __attribute__((ext_vector_type(8)));
typedef float f32x4 __attribute__((ext_vector_type(4)));

__device__ __forceinline__ uint16_t f2b(float f) {
  uint32_t u = __float_as_uint(f);
  u += 0x7FFFu + ((u >> 16) & 1u);
  return (uint16_t)(u >> 16);
}

__device__ __forceinline__ float b2f(uint16_t u) {
  return __uint_as_float((uint32_t)u << 16);
}

__device__ __forceinline__ void gld16(const uint16_t* g, uint16_t* l) {
  __builtin_amdgcn_global_load_lds(
      (const __attribute__((address_space(1))) uint32_t*)g,
      (__attribute__((address_space(3))) uint32_t*)l, 16, 0, 0);
}

__device__ __forceinline__ f32x4 mfma16(bf16x8 a, bf16x8 b, f32x4 c) {
  return __builtin_amdgcn_mfma_f32_16x16x32_bf16(a, b, c, 0, 0, 0);
}

// ---------------- convert f32 -> bf16 ----------------
__global__ __launch_bounds__(256) void cvt4_k(const float* __restrict__ in,
                                              uint16_t* __restrict__ out, int n4) {
  const int gid = blockIdx.x * 256 + threadIdx.x;
  if (gid >= n4) return;
  const float4 v = ((const float4*)in)[gid];
  ushort4 w; w.x = f2b(v.x); w.y = f2b(v.y); w.z = f2b(v.z); w.w = f2b(v.w);
  ((ushort4*)out)[gid] = w;
}

// ---------------- embedding ----------------
__global__ __launch_bounds__(256) void embed_k(const int* __restrict__ idx,
                                               const float* __restrict__ tok,
                                               const float* __restrict__ pos,
                                               float* __restrict__ x) {
  const int gid = blockIdx.x * 256 + threadIdx.x;
  const int row = gid / (CC / 4), c4 = gid % (CC / 4);
  const int t = row & (TT - 1);
  const int tkn = idx[row];
  const float4 a = ((const float4*)(tok + (size_t)tkn * CC))[c4];
  const float4 q = ((const float4*)(pos + (size_t)t * CC))[c4];
  ((float4*)(x + (size_t)row * CC))[c4] =
      make_float4(a.x + q.x, a.y + q.y, a.z + q.z, a.w + q.w);
}

// ---------------- layernorm: fp32 in -> bf16 out ----------------
__global__ __launch_bounds__(256) void ln_k(const float* __restrict__ x,
                                            const float* __restrict__ gamma,
                                            const float* __restrict__ beta,
                                            uint16_t* __restrict__ o) {
  const int lane = threadIdx.x & 63, wid = threadIdx.x >> 6;
  const int row = blockIdx.x * 4 + wid;
  const float4* xr = (const float4*)(x + (size_t)row * CC);
  float4 v[3]; float s = 0.f, sq = 0.f;
#pragma unroll
  for (int i = 0; i < 3; ++i) {
    v[i] = xr[lane + i * 64];
    s += v[i].x + v[i].y + v[i].z + v[i].w;
    sq += v[i].x * v[i].x + v[i].y * v[i].y + v[i].z * v[i].z + v[i].w * v[i].w;
  }
#pragma unroll
  for (int m = 1; m < 64; m <<= 1) { s += __shfl_xor(s, m, 64); sq += __shfl_xor(sq, m, 64); }
  const float mu = s * (1.f / 768.f);
  const float rstd = rsqrtf(sq * (1.f / 768.f) - mu * mu + 1e-5f);
  ushort4* orow = (ushort4*)(o + (size_t)row * CC);
#pragma unroll
  for (int i = 0; i < 3; ++i) {
    const int c4 = lane + i * 64;
    const float4 gg = ((const float4*)gamma)[c4];
    const float4 bb = ((const float4*)beta)[c4];
    ushort4 w;
    w.x = f2b((v[i].x - mu) * rstd * gg.x + bb.x);
    w.y = f2b((v[i].y - mu) * rstd * gg.y + bb.y);
    w.z = f2b((v[i].z - mu) * rstd * gg.z + bb.z);
    w.w = f2b((v[i].w - mu) * rstd * gg.w + bb.w);
    orow[c4] = w;
  }
}

// ------- layernorm + NP bf16-partial reduce: x += sum(p_j); o = LN(x) -------
template <int NP>
__global__ __launch_bounds__(256) void lnrb_k(float* __restrict__ x,
                                              const uint16_t* __restrict__ pp,
                                              const float* __restrict__ gamma,
                                              const float* __restrict__ beta,
                                              uint16_t* __restrict__ o) {
  const int lane = threadIdx.x & 63, wid = threadIdx.x >> 6;
  const int row = blockIdx.x * 4 + wid;
  float4* xr = (float4*)(x + (size_t)row * CC);
  float4 v[3]; float s = 0.f, sq = 0.f;
#pragma unroll
  for (int i = 0; i < 3; ++i) {
    const int c4 = lane + i * 64;
    float4 a = xr[c4];
#pragma unroll
    for (int j = 0; j < NP; ++j) {
      const ushort4 q =
          ((const ushort4*)(pp + (size_t)j * MM * CC + (size_t)row * CC))[c4];
      a.x += b2f(q.x); a.y += b2f(q.y); a.z += b2f(q.z); a.w += b2f(q.w);
    }
    xr[c4] = a;
    v[i] = a;
    s += a.x + a.y + a.z + a.w;
    sq += a.x * a.x + a.y * a.y + a.z * a.z + a.w * a.w;
  }
#pragma unroll
  for (int m = 1; m < 64; m <<= 1) { s += __shfl_xor(s, m, 64); sq += __shfl_xor(sq, m, 64); }
  const float mu = s * (1.f / 768.f);
  const float rstd = rsqrtf(sq * (1.f / 768.f) - mu * mu + 1e-5f);
  ushort4* orow = (ushort4*)(o + (size_t)row * CC);
#pragma unroll
  for (int i = 0; i < 3; ++i) {
    const int c4 = lane + i * 64;
    const float4 gg = ((const float4*)gamma)[c4];
    const float4 bb = ((const float4*)beta)[c4];
    ushort4 w;
    w.x = f2b((v[i].x - mu) * rstd * gg.x + bb.x);
    w.y = f2b((v[i].y - mu) * rstd * gg.y + bb.y);
    w.z = f2b((v[i].z - mu) * rstd * gg.z + bb.z);
    w.w = f2b((v[i].w - mu) * rstd * gg.w + bb.w);
    orow[c4] = w;
  }
}

// ------- all-weights transpose+convert (6 layers x 4 matrices, one launch) -------
__global__ __launch_bounds__(256) void tca_k(const float* __restrict__ Wq,
                                             const float* __restrict__ Wp,
                                             const float* __restrict__ W1p,
                                             const float* __restrict__ W2p,
                                             uint16_t* __restrict__ dq,
                                             uint16_t* __restrict__ dp,
                                             uint16_t* __restrict__ d1,
                                             uint16_t* __restrict__ d2) {
  __shared__ float tile[32][33];
  const int b = blockIdx.x;
  const int l = b / 6912;
  int r = b - l * 6912;
  const float* src; uint16_t* dst; int K, N, kt, nt;
  if (r < 1728) {
    K = CC; N = 3 * CC;
    src = Wq + (size_t)l * CC * 3 * CC; dst = dq + (size_t)l * CC * 3 * CC;
    kt = r / 72; nt = r % 72;
  } else if (r < 2304) {
    r -= 1728; K = CC; N = CC;
    src = Wp + (size_t)l * CC * CC; dst = dp + (size_t)l * CC * CC;
    kt = r / 24; nt = r % 24;
  } else if (r < 4608) {
    r -= 2304; K = CC; N = DFF;
    src = W1p + (size_t)l * CC * DFF; dst = d1 + (size_t)l * CC * DFF;
    kt = r / 96; nt = r % 96;
  } else {
    r -= 4608; K = DFF; N = CC;
    src = W2p + (size_t)l * DFF * CC; dst = d2 + (size_t)l * DFF * CC;
    kt = r / 24; nt = r % 24;
  }
  const int tx = threadIdx.x & 31, ty = threadIdx.x >> 5;
  const int kb = kt * 32, nb = nt * 32;
#pragma unroll
  for (int i = 0; i < 32; i += 8)
    tile[ty + i][tx] = src[(size_t)(kb + ty + i) * N + nb + tx];
  __syncthreads();
#pragma unroll
  for (int i = 0; i < 32; i += 8)
    dst[(size_t)(nb + ty + i) * K + kb + tx] = f2b(tile[tx][ty + i]);
}

// ---------------- 128x128 GEMM, BK=64, chunk-swizzled LDS (m97 structure) ----------------
// 32KB LDS (two 128x64 bf16 tiles). Rows are 128B = 8 chunks of 16B.
// Swizzle: LDS(row, pos) holds global chunk pos ^ (row&7); applied on the
// pre-swizzled global SOURCE (gld16 dest linear, rule 21) and on the read
// position. Bank audit: per ds_read_b128 wave, 64 distinct 16B segments land
// 8 words/bank (the b128 floor) -> no conflict slowdown.
// BK=64 halves the per-K-iter barrier/drain count vs BK=32 (the m97 stall).
// split-K via gridDim.z / blockIdx.z.
// EPI: 1 = f32 store; 2 = bias+GELU -> bf16; 5 = qkv split; 8 = bf16 partials (+bias kp0)
template <int EPI>
__global__ __launch_bounds__(256) void gemm_k(const uint16_t* __restrict__ A,
                                              const uint16_t* __restrict__ Bt,
                                              int N, int K,
                                              const float* __restrict__ bias,
                                              uint16_t* __restrict__ outb,
                                              float* __restrict__ outf) {
  __shared__ __align__(16) uint16_t As[128 * 64];
  __shared__ __align__(16) uint16_t Bs[128 * 64];
  const int tid = threadIdx.x;
  const int lane = tid & 63, wid = tid >> 6;
  const int wm = wid >> 1, wn = wid & 1;
  const int bm = blockIdx.x * 128, bn = blockIdx.y * 128;
  const int kp = blockIdx.z;
  const int Ksub = K / (int)gridDim.z;
  const int k0b = kp * Ksub;
  const int nkt = Ksub >> 6;
  // staging: unit u = q*256+tid -> row q*32+(tid>>3), linear dest u*16B;
  // source chunk pre-swizzled: (tid&7) ^ ((tid>>3)&7)
  const int srow = tid >> 3;
  const int swz = (tid & 7) ^ (srow & 7);
  const uint16_t* gA0 = A + (size_t)(bm + srow) * K + k0b + swz * 8;
  const uint16_t* gB0 = Bt + (size_t)(bn + srow) * K + k0b + swz * 8;
  const size_t qs = (size_t)32 * K;
  const int l15 = lane & 15, lhi = lane >> 4;
  int aof[2][4], bof[2][4];
#pragma unroll
  for (int kk = 0; kk < 2; ++kk)
#pragma unroll
    for (int i = 0; i < 4; ++i) {
      const int sw = ((kk * 4 + lhi) ^ (l15 & 7)) * 16;
      aof[kk][i] = (wm * 64 + i * 16 + l15) * 128 + sw;
      bof[kk][i] = (wn * 64 + i * 16 + l15) * 128 + sw;
    }
  f32x4 acc[4][4] = {};
  for (int t = 0; t < nkt; ++t) {
    const int ko = t * 64;
#pragma unroll
    for (int q = 0; q < 4; ++q) {
      gld16(gA0 + q * qs + ko, &As[q * 2048 + tid * 8]);
      gld16(gB0 + q * qs + ko, &Bs[q * 2048 + tid * 8]);
    }
    __syncthreads();
    const char* Ab = (const char*)As;
    const char* Bb = (const char*)Bs;
#pragma unroll
    for (int kk = 0; kk < 2; ++kk) {
      bf16x8 a[4], b[4];
#pragma unroll
      for (int i = 0; i < 4; ++i) {
        a[i] = *(const bf16x8*)(Ab + aof[kk][i]);
        b[i] = *(const bf16x8*)(Bb + bof[kk][i]);
      }
#pragma unroll
      for (int i = 0; i < 4; ++i)
#pragma unroll
        for (int j = 0; j < 4; ++j)
          acc[i][j] = mfma16(a[i], b[j], acc[i][j]);
    }
    __syncthreads();
  }
#pragma unroll
  for (int i = 0; i < 4; ++i) {
    const int m0 = bm + wm * 64 + i * 16 + (lhi << 2);
#pragma unroll
    for (int j = 0; j < 4; ++j) {
      const int n = bn + wn * 64 + j * 16 + l15;
      if constexpr (EPI == 5) {
        const int sec = n / CC;
        const int rn = n - sec * CC;
        const int hh = rn >> 6, d = rn & 63;
        const int b = m0 >> 10, t0 = m0 & 1023;
        if (sec == 2) {
          ushort4 w;
          w.x = f2b(acc[i][j][0]); w.y = f2b(acc[i][j][1]);
          w.z = f2b(acc[i][j][2]); w.w = f2b(acc[i][j][3]);
          *(ushort4*)(outb + 2 * QKREG + ((size_t)(b * HH + hh) * 64 + d) * TT + t0) = w;
        } else {
          uint16_t* dst = outb + (size_t)sec * QKREG + ((size_t)(b * HH + hh) * TT + t0) * 64 + d;
#pragma unroll
          for (int rr = 0; rr < 4; ++rr) dst[(size_t)rr * 64] = f2b(acc[i][j][rr]);
        }
      } else if constexpr (EPI == 8) {
        uint16_t* pdst = outb + (size_t)kp * ((size_t)MM * N);
        const float bb = (kp == 0 && bias) ? bias[n] : 0.f;
#pragma unroll
        for (int rr = 0; rr < 4; ++rr)
          pdst[(size_t)(m0 + rr) * N + n] = f2b(acc[i][j][rr] + bb);
      } else {
#pragma unroll
        for (int rr = 0; rr < 4; ++rr) {
          const size_t o = (size_t)(m0 + rr) * N + n;
          const float v = acc[i][j][rr];
          if constexpr (EPI == 1) {
            outf[o] = v;
          } else if constexpr (EPI == 2) {
            float t = v + bias[n];
            t = 0.5f * t * (1.0f + erff(t * 0.70710678118654752f));
            outb[o] = f2b(t);
          }
        }
      }
    }
  }
}

// ---------------- fused causal flash attention ----------------
__global__ __launch_bounds__(256) void attn_k(const uint16_t* __restrict__ qkvh,
                                              uint16_t* __restrict__ ao) {
  __shared__ __align__(16) uint16_t Ks[64 * 64], Vs[64 * 64];
  __shared__ __align__(16) uint16_t Ps[4][16 * 64];
  const int tid = threadIdx.x, lane = tid & 63, wid = tid >> 6;
  const int qt = (TT / 64 - 1) - blockIdx.x / (BB * HH);
  const int bh = blockIdx.x % (BB * HH);
  const uint16_t* qb = qkvh + (size_t)bh * (TT * 64);
  const uint16_t* kb = qkvh + QKREG + (size_t)bh * (TT * 64);
  const uint16_t* vb = qkvh + 2 * QKREG + (size_t)bh * ((size_t)64 * TT);
  const int l15 = lane & 15, lhi = lane >> 4;
  bf16x8 qf[2];
  {
    const uint16_t* qr = qb + (size_t)(qt * 64 + wid * 16 + l15) * 64 + lhi * 8;
    qf[0] = *(const bf16x8*)qr;
    qf[1] = *(const bf16x8*)(qr + 32);
  }
  const int c0 = tid, c1 = tid + 256;
  const int r0 = c0 >> 3, r1 = c1 >> 3;
  const int cb0 = (c0 & 7) * 16, cb1 = (c1 & 7) * 16;
  const int ph0 = r0 * 128 + (cb0 ^ ((r0 & 7) << 4));
  const int ph1 = r1 * 128 + (cb1 ^ ((r1 & 7) << 4));

  uint4 kr0, kr1, vr0, vr1;
  kr0 = *(const uint4*)(kb + (size_t)r0 * 64 + cb0 / 2);
  kr1 = *(const uint4*)(kb + (size_t)r1 * 64 + cb1 / 2);
  vr0 = *(const uint4*)(vb + (size_t)r0 * TT + cb0 / 2);
  vr1 = *(const uint4*)(vb + (size_t)r1 * TT + cb1 / 2);
  *(uint4*)((char*)Ks + ph0) = kr0;
  *(uint4*)((char*)Ks + ph1) = kr1;
  *(uint4*)((char*)Vs + ph0) = vr0;
  *(uint4*)((char*)Vs + ph1) = vr1;
  __syncthreads();

  f32x4 oacc[4] = {};
  float mrun[4] = {-INFINITY, -INFINITY, -INFINITY, -INFINITY};
  float lrun[4] = {0.f, 0.f, 0.f, 0.f};
  char* pb = (char*)Ps[wid];

  for (int j = 0; j <= qt; ++j) {
    const bool more = (j < qt);
    if (more) {
      const int jn = (j + 1) * 64;
      kr0 = *(const uint4*)(kb + (size_t)(jn + r0) * 64 + cb0 / 2);
      kr1 = *(const uint4*)(kb + (size_t)(jn + r1) * 64 + cb1 / 2);
      vr0 = *(const uint4*)(vb + (size_t)r0 * TT + jn + cb0 / 2);
      vr1 = *(const uint4*)(vb + (size_t)r1 * TT + jn + cb1 / 2);
    }
    f32x4 s4[4] = {};
    __builtin_amdgcn_s_setprio(1);
#pragma unroll
    for (int kk = 0; kk < 2; ++kk) {
      const int cbyte = kk * 64 + lhi * 16;
#pragma unroll
      for (int nt = 0; nt < 4; ++nt) {
        const int krow = nt * 16 + l15;
        const bf16x8 kf = *(const bf16x8*)((char*)Ks + krow * 128 + (cbyte ^ ((krow & 7) << 4)));
        s4[nt] = mfma16(qf[kk], kf, s4[nt]);
      }
    }
    __builtin_amdgcn_s_setprio(0);
    const bool diag = (j == qt);
    float alpha[4];
#pragma unroll
    for (int r = 0; r < 4; ++r) {
      const int qg = qt * 64 + wid * 16 + (lhi << 2) + r;
      float mx = -INFINITY;
#pragma unroll
      for (int nt = 0; nt < 4; ++nt) {
        float v = s4[nt][r] * 0.125f;
        if (diag && (j * 64 + nt * 16 + l15) > qg) v = -INFINITY;
        s4[nt][r] = v;
        mx = fmaxf(mx, v);
      }
#pragma unroll
      for (int m = 1; m < 16; m <<= 1) mx = fmaxf(mx, __shfl_xor(mx, m, 16));
      const float mnew = fmaxf(mrun[r], mx);
      alpha[r] = __expf(mrun[r] - mnew);
      float ps = 0.f;
#pragma unroll
      for (int nt = 0; nt < 4; ++nt) {
        const float pp = __expf(s4[nt][r] - mnew);
        s4[nt][r] = pp;
        ps += pp;
      }
#pragma unroll
      for (int m = 1; m < 16; m <<= 1) ps += __shfl_xor(ps, m, 16);
      lrun[r] = lrun[r] * alpha[r] + ps;
      mrun[r] = mnew;
    }
#pragma unroll
    for (int dt = 0; dt < 4; ++dt)
#pragma unroll
      for (int r = 0; r < 4; ++r) oacc[dt][r] *= alpha[r];
#pragma unroll
    for (int r = 0; r < 4; ++r) {
      const int prow = (lhi << 2) + r;
      const int swp = (prow & 7) << 4;
#pragma unroll
      for (int nt = 0; nt < 4; ++nt) {
        const int cb = (nt * 16 + l15) * 2;
        *(uint16_t*)(pb + prow * 128 + (cb ^ swp)) = f2b(s4[nt][r]);
      }
    }
    __builtin_amdgcn_s_setprio(1);
#pragma unroll
    for (int kk = 0; kk < 2; ++kk) {
      const int cbyte = kk * 64 + lhi * 16;
      const bf16x8 pf = *(const bf16x8*)(pb + l15 * 128 + (cbyte ^ ((l15 & 7) << 4)));
#pragma unroll
      for (int dt = 0; dt < 4; ++dt) {
        const int vrow = dt * 16 + l15;
        const bf16x8 vf = *(const bf16x8*)((char*)Vs + vrow * 128 + (cbyte ^ ((vrow & 7) << 4)));
        oacc[dt] = mfma16(pf, vf, oacc[dt]);
      }
    }
    __builtin_amdgcn_s_setprio(0);
    __syncthreads();
    if (more) {
      *(uint4*)((char*)Ks + ph0) = kr0;
      *(uint4*)((char*)Ks + ph1) = kr1;
      *(uint4*)((char*)Vs + ph0) = vr0;
      *(uint4*)((char*)Vs + ph1) = vr1;
    }
    __syncthreads();
  }
#pragma unroll
  for (int dt = 0; dt < 4; ++dt) {
#pragma unroll
    for (int r = 0; r < 4; ++r) {
      const int q = qt * 64 + wid * 16 + (lhi << 2) + r;
      const float v = oacc[dt][r] / lrun[r];
      ao[(size_t)((bh / HH) * TT + q) * CC + (bh % HH) * HDIM + dt * 16 + l15] = f2b(v);
    }
  }
}

extern "C" void kernel_launch(void* const* d_in, const int* in_sizes, int n_in,
                              void* d_out, int out_size, void* d_ws, size_t ws_size,
                              hipStream_t stream) {
  (void)in_sizes; (void)n_in; (void)out_size;
  const int*   idx  = (const int*)d_in[0];
  const float* tok  = (const float*)d_in[1];
  const float* pos  = (const float*)d_in[2];
  const float* Wqkv = (const float*)d_in[3];
  const float* Wpro = (const float*)d_in[4];
  const float* W1   = (const float*)d_in[5];
  const float* b1   = (const float*)d_in[6];
  const float* W2   = (const float*)d_in[7];
  const float* b2   = (const float*)d_in[8];
  const float* g1   = (const float*)d_in[9];
  const float* be1  = (const float*)d_in[10];
  const float* g2   = (const float*)d_in[11];
  const float* be2  = (const float*)d_in[12];
  const float* gf   = (const float*)d_in[13];
  const float* bfb  = (const float*)d_in[14];
  float* out = (float*)d_out;

  const size_t QS = (size_t)CC * 3 * CC;
  const size_t PS = (size_t)CC * CC;
  const size_t S1 = (size_t)CC * DFF;
  const size_t S2 = (size_t)DFF * CC;

  char* p = (char*)d_ws;
  float* x = (float*)p;            p += (size_t)MM * CC * 4;
  uint16_t* act = (uint16_t*)p;    p += (size_t)MM * CC * 2;
  uint16_t* big = (uint16_t*)p;    p += (size_t)MM * DFF * 2;
  uint16_t* tokb = (uint16_t*)p;   p += (size_t)VV * CC * 2;
  uint16_t* partb = (uint16_t*)p;  p += (size_t)2 * MM * CC * 2;   // bf16 split-K partials
  char* pbase = p;
  uint16_t* wqA = (uint16_t*)p;    p += QS * LNUM * 2;
  uint16_t* wpA = (uint16_t*)p;    p += PS * LNUM * 2;
  uint16_t* w1A = (uint16_t*)p;    p += S1 * LNUM * 2;
  uint16_t* w2A = (uint16_t*)p;    p += S2 * LNUM * 2;
  const bool roomy2 = ws_size >= (size_t)(p - (char*)d_ws);
  if (!roomy2) {
    p = pbase;
    wqA = (uint16_t*)p; p += QS * 2;
    wpA = (uint16_t*)p; p += PS * 2;
    w1A = (uint16_t*)p; p += S1 * 2;
    w2A = (uint16_t*)p; p += S2 * 2;
  }

  cvt4_k<<<dim3((VV * CC / 4 + 255) / 256), 256, 0, stream>>>(tok, tokb, VV * CC / 4);
  embed_k<<<dim3(MM * (CC / 4) / 256), 256, 0, stream>>>(idx, tok, pos, x);
  ln_k<<<dim3(MM / 4), 256, 0, stream>>>(x, g1, be1, act);
  if (roomy2)
    tca_k<<<dim3(LNUM * 6912), 256, 0, stream>>>(Wqkv, Wpro, W1, W2, wqA, wpA, w1A, w2A);

  for (int l = 0; l < LNUM; ++l) {
    if (!roomy2)
      tca_k<<<dim3(6912), 256, 0, stream>>>(Wqkv + (size_t)l * QS, Wpro + (size_t)l * PS,
                                            W1 + (size_t)l * S1, W2 + (size_t)l * S2,
                                            wqA, wpA, w1A, w2A);
    const size_t lw = roomy2 ? (size_t)l : 0;
    // QKV: 64x18 = 1152 blocks (4.5/CU), nkt=12
    gemm_k<5><<<dim3(MM / 128, 3 * CC / 128, 1), 256, 0, stream>>>(
        act, wqA + lw * QS, 3 * CC, CC, nullptr, big, nullptr);
    attn_k<<<dim3((TT / 64) * BB * HH), 256, 0, stream>>>(big, act);
    // proj: split-K2 bf16 partials -> 768 blocks (3/CU), nkt=6
    gemm_k<8><<<dim3(MM / 128, CC / 128, 2), 256, 0, stream>>>(
        act, wpA + lw * PS, CC, CC, nullptr, partb, nullptr);
    lnrb_k<2><<<dim3(MM / 4), 256, 0, stream>>>(x, partb,
                                                g2 + (size_t)l * CC, be2 + (size_t)l * CC, act);
    // W1 + GELU: 1536 blocks (6/CU), nkt=12
    gemm_k<2><<<dim3(MM / 128, DFF / 128, 1), 256, 0, stream>>>(
        act, w1A + lw * S1, DFF, CC, b1 + (size_t)l * DFF, big, nullptr);
    // W2: split-K2 bf16 partials -> 768 blocks, nkt=24
    const float* ng = (l + 1 < LNUM) ? g1 + (size_t)(l + 1) * CC : gf;
    const float* nb = (l + 1 < LNUM) ? be1 + (size_t)(l + 1) * CC : bfb;
    gemm_k<8><<<dim3(MM / 128, CC / 128, 2), 256, 0, stream>>>(
        big, w2A + lw * S2, CC, DFF, b2 + (size_t)l * CC, partb, nullptr);
    lnrb_k<2><<<dim3(MM / 4), 256, 0, stream>>>(x, partb, ng, nb, act);
  }
  gemm_k<1><<<dim3(MM / 128, VV / 128, 1), 256, 0, stream>>>(
      act, tokb, VV, CC, nullptr, nullptr, out);
}

// Round 13
// 1462.706 us; speedup vs baseline: 1.2172x; 1.0476x over previous
//
#include <hip/hip_runtime.h>
#include <hip/hip_bf16.h>
#include <stdint.h>

#define LNUM 6
#define BB 8
#define TT 1024
#define CC 768
#define HH 12
#define HDIM 64
#define DFF 3072
#define VV 512
#define MM (BB*TT)
#define QKREG ((size_t)BB*HH*TT*64)

typedef __bf16 bf16x8 __attribute__((ext_vector_type(8)));
typedef float f32x4 __attribute__((ext_vector_type(4)));

__device__ __forceinline__ uint16_t f2b(float f) {
  uint32_t u = __float_as_uint(f);
  u += 0x7FFFu + ((u >> 16) & 1u);
  return (uint16_t)(u >> 16);
}

__device__ __forceinline__ float b2f(uint16_t u) {
  return __uint_as_float((uint32_t)u << 16);
}

__device__ __forceinline__ void gld16(const uint16_t* g, uint16_t* l) {
  __builtin_amdgcn_global_load_lds(
      (const __attribute__((address_space(1))) uint32_t*)g,
      (__attribute__((address_space(3))) uint32_t*)l, 16, 0, 0);
}

__device__ __forceinline__ f32x4 mfma16(bf16x8 a, bf16x8 b, f32x4 c) {
  return __builtin_amdgcn_mfma_f32_16x16x32_bf16(a, b, c, 0, 0, 0);
}

// ---------------- convert f32 -> bf16 ----------------
__global__ __launch_bounds__(256) void cvt4_k(const float* __restrict__ in,
                                              uint16_t* __restrict__ out, int n4) {
  const int gid = blockIdx.x * 256 + threadIdx.x;
  if (gid >= n4) return;
  const float4 v = ((const float4*)in)[gid];
  ushort4 w; w.x = f2b(v.x); w.y = f2b(v.y); w.z = f2b(v.z); w.w = f2b(v.w);
  ((ushort4*)out)[gid] = w;
}

// ---------------- embedding: x(bf16) = tok_emb[idx] + pos_emb ----------------
__global__ __launch_bounds__(256) void embed_k(const int* __restrict__ idx,
                                               const float* __restrict__ tok,
                                               const float* __restrict__ pos,
                                               uint16_t* __restrict__ x) {
  const int gid = blockIdx.x * 256 + threadIdx.x;
  const int row = gid / (CC / 4), c4 = gid % (CC / 4);
  const int t = row & (TT - 1);
  const int tkn = idx[row];
  const float4 a = ((const float4*)(tok + (size_t)tkn * CC))[c4];
  const float4 q = ((const float4*)(pos + (size_t)t * CC))[c4];
  ushort4 w;
  w.x = f2b(a.x + q.x); w.y = f2b(a.y + q.y);
  w.z = f2b(a.z + q.z); w.w = f2b(a.w + q.w);
  ((ushort4*)(x + (size_t)row * CC))[c4] = w;
}

// ---------------- layernorm: bf16 x in -> bf16 out ----------------
__global__ __launch_bounds__(256) void ln_k(const uint16_t* __restrict__ x,
                                            const float* __restrict__ gamma,
                                            const float* __restrict__ beta,
                                            uint16_t* __restrict__ o) {
  const int lane = threadIdx.x & 63, wid = threadIdx.x >> 6;
  const int row = blockIdx.x * 4 + wid;
  const ushort4* xr = (const ushort4*)(x + (size_t)row * CC);
  float4 v[3]; float s = 0.f, sq = 0.f;
#pragma unroll
  for (int i = 0; i < 3; ++i) {
    const ushort4 u = xr[lane + i * 64];
    v[i] = make_float4(b2f(u.x), b2f(u.y), b2f(u.z), b2f(u.w));
    s += v[i].x + v[i].y + v[i].z + v[i].w;
    sq += v[i].x * v[i].x + v[i].y * v[i].y + v[i].z * v[i].z + v[i].w * v[i].w;
  }
#pragma unroll
  for (int m = 1; m < 64; m <<= 1) { s += __shfl_xor(s, m, 64); sq += __shfl_xor(sq, m, 64); }
  const float mu = s * (1.f / 768.f);
  const float rstd = rsqrtf(sq * (1.f / 768.f) - mu * mu + 1e-5f);
  ushort4* orow = (ushort4*)(o + (size_t)row * CC);
#pragma unroll
  for (int i = 0; i < 3; ++i) {
    const int c4 = lane + i * 64;
    const float4 gg = ((const float4*)gamma)[c4];
    const float4 bb = ((const float4*)beta)[c4];
    ushort4 w;
    w.x = f2b((v[i].x - mu) * rstd * gg.x + bb.x);
    w.y = f2b((v[i].y - mu) * rstd * gg.y + bb.y);
    w.z = f2b((v[i].z - mu) * rstd * gg.z + bb.z);
    w.w = f2b((v[i].w - mu) * rstd * gg.w + bb.w);
    orow[c4] = w;
  }
}

// --- layernorm + NP bf16-partial reduce: x(bf16) += sum(p_j); o = LN(x) ---
template <int NP>
__global__ __launch_bounds__(256) void lnrb_k(uint16_t* __restrict__ x,
                                              const uint16_t* __restrict__ pp,
                                              const float* __restrict__ gamma,
                                              const float* __restrict__ beta,
                                              uint16_t* __restrict__ o) {
  const int lane = threadIdx.x & 63, wid = threadIdx.x >> 6;
  const int row = blockIdx.x * 4 + wid;
  ushort4* xr = (ushort4*)(x + (size_t)row * CC);
  float4 v[3]; float s = 0.f, sq = 0.f;
#pragma unroll
  for (int i = 0; i < 3; ++i) {
    const int c4 = lane + i * 64;
    const ushort4 u = xr[c4];
    float4 a = make_float4(b2f(u.x), b2f(u.y), b2f(u.z), b2f(u.w));
#pragma unroll
    for (int j = 0; j < NP; ++j) {
      const ushort4 q =
          ((const ushort4*)(pp + (size_t)j * MM * CC + (size_t)row * CC))[c4];
      a.x += b2f(q.x); a.y += b2f(q.y); a.z += b2f(q.z); a.w += b2f(q.w);
    }
    ushort4 w;
    w.x = f2b(a.x); w.y = f2b(a.y); w.z = f2b(a.z); w.w = f2b(a.w);
    xr[c4] = w;
    v[i] = a;
    s += a.x + a.y + a.z + a.w;
    sq += a.x * a.x + a.y * a.y + a.z * a.z + a.w * a.w;
  }
#pragma unroll
  for (int m = 1; m < 64; m <<= 1) { s += __shfl_xor(s, m, 64); sq += __shfl_xor(sq, m, 64); }
  const float mu = s * (1.f / 768.f);
  const float rstd = rsqrtf(sq * (1.f / 768.f) - mu * mu + 1e-5f);
  ushort4* orow = (ushort4*)(o + (size_t)row * CC);
#pragma unroll
  for (int i = 0; i < 3; ++i) {
    const int c4 = lane + i * 64;
    const float4 gg = ((const float4*)gamma)[c4];
    const float4 bb = ((const float4*)beta)[c4];
    ushort4 w;
    w.x = f2b((v[i].x - mu) * rstd * gg.x + bb.x);
    w.y = f2b((v[i].y - mu) * rstd * gg.y + bb.y);
    w.z = f2b((v[i].z - mu) * rstd * gg.z + bb.z);
    w.w = f2b((v[i].w - mu) * rstd * gg.w + bb.w);
    orow[c4] = w;
  }
}

// ------- all-weights transpose+convert (6 layers x 4 matrices, one launch) -------
__global__ __launch_bounds__(256) void tca_k(const float* __restrict__ Wq,
                                             const float* __restrict__ Wp,
                                             const float* __restrict__ W1p,
                                             const float* __restrict__ W2p,
                                             uint16_t* __restrict__ dq,
                                             uint16_t* __restrict__ dp,
                                             uint16_t* __restrict__ d1,
                                             uint16_t* __restrict__ d2) {
  __shared__ float tile[32][33];
  const int b = blockIdx.x;
  const int l = b / 6912;
  int r = b - l * 6912;
  const float* src; uint16_t* dst; int K, N, kt, nt;
  if (r < 1728) {
    K = CC; N = 3 * CC;
    src = Wq + (size_t)l * CC * 3 * CC; dst = dq + (size_t)l * CC * 3 * CC;
    kt = r / 72; nt = r % 72;
  } else if (r < 2304) {
    r -= 1728; K = CC; N = CC;
    src = Wp + (size_t)l * CC * CC; dst = dp + (size_t)l * CC * CC;
    kt = r / 24; nt = r % 24;
  } else if (r < 4608) {
    r -= 2304; K = CC; N = DFF;
    src = W1p + (size_t)l * CC * DFF; dst = d1 + (size_t)l * CC * DFF;
    kt = r / 96; nt = r % 96;
  } else {
    r -= 4608; K = DFF; N = CC;
    src = W2p + (size_t)l * DFF * CC; dst = d2 + (size_t)l * DFF * CC;
    kt = r / 24; nt = r % 24;
  }
  const int tx = threadIdx.x & 31, ty = threadIdx.x >> 5;
  const int kb = kt * 32, nb = nt * 32;
#pragma unroll
  for (int i = 0; i < 32; i += 8)
    tile[ty + i][tx] = src[(size_t)(kb + ty + i) * N + nb + tx];
  __syncthreads();
#pragma unroll
  for (int i = 0; i < 32; i += 8)
    dst[(size_t)(nb + ty + i) * K + kb + tx] = f2b(tile[tx][ty + i]);
}

// ---------------- 128x128 GEMM, BK=64, chunk-swizzled LDS (m97 structure) ----------------
// EPI: 1 = f32 store; 2 = bias+GELU -> bf16; 5 = qkv split; 8 = bf16 partials (+bias kp0)
template <int EPI>
__global__ __launch_bounds__(256) void gemm_k(const uint16_t* __restrict__ A,
                                              const uint16_t* __restrict__ Bt,
                                              int N, int K,
                                              const float* __restrict__ bias,
                                              uint16_t* __restrict__ outb,
                                              float* __restrict__ outf) {
  __shared__ __align__(16) uint16_t As[128 * 64];
  __shared__ __align__(16) uint16_t Bs[128 * 64];
  const int tid = threadIdx.x;
  const int lane = tid & 63, wid = tid >> 6;
  const int wm = wid >> 1, wn = wid & 1;
  const int bm = blockIdx.x * 128, bn = blockIdx.y * 128;
  const int kp = blockIdx.z;
  const int Ksub = K / (int)gridDim.z;
  const int k0b = kp * Ksub;
  const int nkt = Ksub >> 6;
  const int srow = tid >> 3;
  const int swz = (tid & 7) ^ (srow & 7);
  const uint16_t* gA0 = A + (size_t)(bm + srow) * K + k0b + swz * 8;
  const uint16_t* gB0 = Bt + (size_t)(bn + srow) * K + k0b + swz * 8;
  const size_t qs = (size_t)32 * K;
  const int l15 = lane & 15, lhi = lane >> 4;
  int aof[2][4], bof[2][4];
#pragma unroll
  for (int kk = 0; kk < 2; ++kk)
#pragma unroll
    for (int i = 0; i < 4; ++i) {
      const int sw = ((kk * 4 + lhi) ^ (l15 & 7)) * 16;
      aof[kk][i] = (wm * 64 + i * 16 + l15) * 128 + sw;
      bof[kk][i] = (wn * 64 + i * 16 + l15) * 128 + sw;
    }
  f32x4 acc[4][4] = {};
  for (int t = 0; t < nkt; ++t) {
    const int ko = t * 64;
#pragma unroll
    for (int q = 0; q < 4; ++q) {
      gld16(gA0 + q * qs + ko, &As[q * 2048 + tid * 8]);
      gld16(gB0 + q * qs + ko, &Bs[q * 2048 + tid * 8]);
    }
    __syncthreads();
    const char* Ab = (const char*)As;
    const char* Bb = (const char*)Bs;
#pragma unroll
    for (int kk = 0; kk < 2; ++kk) {
      bf16x8 a[4], b[4];
#pragma unroll
      for (int i = 0; i < 4; ++i) {
        a[i] = *(const bf16x8*)(Ab + aof[kk][i]);
        b[i] = *(const bf16x8*)(Bb + bof[kk][i]);
      }
#pragma unroll
      for (int i = 0; i < 4; ++i)
#pragma unroll
        for (int j = 0; j < 4; ++j)
          acc[i][j] = mfma16(a[i], b[j], acc[i][j]);
    }
    __syncthreads();
  }
#pragma unroll
  for (int i = 0; i < 4; ++i) {
    const int m0 = bm + wm * 64 + i * 16 + (lhi << 2);
#pragma unroll
    for (int j = 0; j < 4; ++j) {
      const int n = bn + wn * 64 + j * 16 + l15;
      if constexpr (EPI == 5) {
        const int sec = n / CC;
        const int rn = n - sec * CC;
        const int hh = rn >> 6, d = rn & 63;
        const int b = m0 >> 10, t0 = m0 & 1023;
        if (sec == 2) {
          ushort4 w;
          w.x = f2b(acc[i][j][0]); w.y = f2b(acc[i][j][1]);
          w.z = f2b(acc[i][j][2]); w.w = f2b(acc[i][j][3]);
          *(ushort4*)(outb + 2 * QKREG + ((size_t)(b * HH + hh) * 64 + d) * TT + t0) = w;
        } else {
          uint16_t* dst = outb + (size_t)sec * QKREG + ((size_t)(b * HH + hh) * TT + t0) * 64 + d;
#pragma unroll
          for (int rr = 0; rr < 4; ++rr) dst[(size_t)rr * 64] = f2b(acc[i][j][rr]);
        }
      } else if constexpr (EPI == 8) {
        uint16_t* pdst = outb + (size_t)kp * ((size_t)MM * N);
        const float bb = (kp == 0 && bias) ? bias[n] : 0.f;
#pragma unroll
        for (int rr = 0; rr < 4; ++rr)
          pdst[(size_t)(m0 + rr) * N + n] = f2b(acc[i][j][rr] + bb);
      } else {
#pragma unroll
        for (int rr = 0; rr < 4; ++rr) {
          const size_t o = (size_t)(m0 + rr) * N + n;
          const float v = acc[i][j][rr];
          if constexpr (EPI == 1) {
            outf[o] = v;
          } else if constexpr (EPI == 2) {
            float t = v + bias[n];
            t = 0.5f * t * (1.0f + erff(t * 0.70710678118654752f));
            outb[o] = f2b(t);
          }
        }
      }
    }
  }
}

// ---------------- fused causal flash attention (dbuf K/V, 1 barrier/tile) ----------------
__global__ __launch_bounds__(256) void attn_k(const uint16_t* __restrict__ qkvh,
                                              uint16_t* __restrict__ ao) {
  __shared__ __align__(16) uint16_t Ks[2][64 * 64], Vs[2][64 * 64];
  __shared__ __align__(16) uint16_t Ps[4][16 * 64];
  const int tid = threadIdx.x, lane = tid & 63, wid = tid >> 6;
  const int qt = (TT / 64 - 1) - blockIdx.x / (BB * HH);
  const int bh = blockIdx.x % (BB * HH);
  const uint16_t* qb = qkvh + (size_t)bh * (TT * 64);
  const uint16_t* kb = qkvh + QKREG + (size_t)bh * (TT * 64);
  const uint16_t* vb = qkvh + 2 * QKREG + (size_t)bh * ((size_t)64 * TT);
  const int l15 = lane & 15, lhi = lane >> 4;
  bf16x8 qf[2];
  {
    const uint16_t* qr = qb + (size_t)(qt * 64 + wid * 16 + l15) * 64 + lhi * 8;
    qf[0] = *(const bf16x8*)qr;
    qf[1] = *(const bf16x8*)(qr + 32);
  }
  const int c0 = tid, c1 = tid + 256;
  const int r0 = c0 >> 3, r1 = c1 >> 3;
  const int cb0 = (c0 & 7) * 16, cb1 = (c1 & 7) * 16;
  const int ph0 = r0 * 128 + (cb0 ^ ((r0 & 7) << 4));
  const int ph1 = r1 * 128 + (cb1 ^ ((r1 & 7) << 4));

  uint4 kr0, kr1, vr0, vr1;
  // prologue: tile 0 -> buf 0
  kr0 = *(const uint4*)(kb + (size_t)r0 * 64 + cb0 / 2);
  kr1 = *(const uint4*)(kb + (size_t)r1 * 64 + cb1 / 2);
  vr0 = *(const uint4*)(vb + (size_t)r0 * TT + cb0 / 2);
  vr1 = *(const uint4*)(vb + (size_t)r1 * TT + cb1 / 2);
  *(uint4*)((char*)Ks[0] + ph0) = kr0;
  *(uint4*)((char*)Ks[0] + ph1) = kr1;
  *(uint4*)((char*)Vs[0] + ph0) = vr0;
  *(uint4*)((char*)Vs[0] + ph1) = vr1;

  f32x4 oacc[4] = {};
  float mrun[4] = {-INFINITY, -INFINITY, -INFINITY, -INFINITY};
  float lrun[4] = {0.f, 0.f, 0.f, 0.f};
  char* pb = (char*)Ps[wid];

  for (int j = 0; j <= qt; ++j) {
    const int cur = j & 1;
    const bool more = (j < qt);
    // single collective barrier per tile: makes buf[cur] stores (iter j-1 or
    // prologue) visible, and guarantees all waves finished reading buf[cur^1]
    // (iter j-1) before this iter's end-of-loop stores overwrite it.
    __syncthreads();
    if (more) {  // prefetch tile j+1 into regs (overlaps compute)
      const int jn = (j + 1) * 64;
      kr0 = *(const uint4*)(kb + (size_t)(jn + r0) * 64 + cb0 / 2);
      kr1 = *(const uint4*)(kb + (size_t)(jn + r1) * 64 + cb1 / 2);
      vr0 = *(const uint4*)(vb + (size_t)r0 * TT + jn + cb0 / 2);
      vr1 = *(const uint4*)(vb + (size_t)r1 * TT + jn + cb1 / 2);
    }
    const char* Kb = (const char*)Ks[cur];
    const char* Vb = (const char*)Vs[cur];
    f32x4 s4[4] = {};
    __builtin_amdgcn_s_setprio(1);
#pragma unroll
    for (int kk = 0; kk < 2; ++kk) {
      const int cbyte = kk * 64 + lhi * 16;
#pragma unroll
      for (int nt = 0; nt < 4; ++nt) {
        const int krow = nt * 16 + l15;
        const bf16x8 kf = *(const bf16x8*)(Kb + krow * 128 + (cbyte ^ ((krow & 7) << 4)));
        s4[nt] = mfma16(qf[kk], kf, s4[nt]);
      }
    }
    __builtin_amdgcn_s_setprio(0);
    const bool diag = (j == qt);
    float alpha[4];
#pragma unroll
    for (int r = 0; r < 4; ++r) {
      const int qg = qt * 64 + wid * 16 + (lhi << 2) + r;
      float mx = -INFINITY;
#pragma unroll
      for (int nt = 0; nt < 4; ++nt) {
        float v = s4[nt][r] * 0.125f;
        if (diag && (j * 64 + nt * 16 + l15) > qg) v = -INFINITY;
        s4[nt][r] = v;
        mx = fmaxf(mx, v);
      }
#pragma unroll
      for (int m = 1; m < 16; m <<= 1) mx = fmaxf(mx, __shfl_xor(mx, m, 16));
      const float mnew = fmaxf(mrun[r], mx);
      alpha[r] = __expf(mrun[r] - mnew);
      float ps = 0.f;
#pragma unroll
      for (int nt = 0; nt < 4; ++nt) {
        const float pp = __expf(s4[nt][r] - mnew);
        s4[nt][r] = pp;
        ps += pp;
      }
#pragma unroll
      for (int m = 1; m < 16; m <<= 1) ps += __shfl_xor(ps, m, 16);
      lrun[r] = lrun[r] * alpha[r] + ps;
      mrun[r] = mnew;
    }
#pragma unroll
    for (int dt = 0; dt < 4; ++dt)
#pragma unroll
      for (int r = 0; r < 4; ++r) oacc[dt][r] *= alpha[r];
#pragma unroll
    for (int r = 0; r < 4; ++r) {
      const int prow = (lhi << 2) + r;
      const int swp = (prow & 7) << 4;
#pragma unroll
      for (int nt = 0; nt < 4; ++nt) {
        const int cb = (nt * 16 + l15) * 2;
        *(uint16_t*)(pb + prow * 128 + (cb ^ swp)) = f2b(s4[nt][r]);
      }
    }
    __builtin_amdgcn_s_setprio(1);
#pragma unroll
    for (int kk = 0; kk < 2; ++kk) {
      const int cbyte = kk * 64 + lhi * 16;
      const bf16x8 pf = *(const bf16x8*)(pb + l15 * 128 + (cbyte ^ ((l15 & 7) << 4)));
#pragma unroll
      for (int dt = 0; dt < 4; ++dt) {
        const int vrow = dt * 16 + l15;
        const bf16x8 vf = *(const bf16x8*)(Vb + vrow * 128 + (cbyte ^ ((vrow & 7) << 4)));
        oacc[dt] = mfma16(pf, vf, oacc[dt]);
      }
    }
    __builtin_amdgcn_s_setprio(0);
    if (more) {  // commit prefetched tile to the other buffer (no barrier here)
      char* kn = (char*)Ks[cur ^ 1];
      char* vn = (char*)Vs[cur ^ 1];
      *(uint4*)(kn + ph0) = kr0;
      *(uint4*)(kn + ph1) = kr1;
      *(uint4*)(vn + ph0) = vr0;
      *(uint4*)(vn + ph1) = vr1;
    }
  }
#pragma unroll
  for (int dt = 0; dt < 4; ++dt) {
#pragma unroll
    for (int r = 0; r < 4; ++r) {
      const int q = qt * 64 + wid * 16 + (lhi << 2) + r;
      const float v = oacc[dt][r] / lrun[r];
      ao[(size_t)((bh / HH) * TT + q) * CC + (bh % HH) * HDIM + dt * 16 + l15] = f2b(v);
    }
  }
}

extern "C" void kernel_launch(void* const* d_in, const int* in_sizes, int n_in,
                              void* d_out, int out_size, void* d_ws, size_t ws_size,
                              hipStream_t stream) {
  (void)in_sizes; (void)n_in; (void)out_size;
  const int*   idx  = (const int*)d_in[0];
  const float* tok  = (const float*)d_in[1];
  const float* pos  = (const float*)d_in[2];
  const float* Wqkv = (const float*)d_in[3];
  const float* Wpro = (const float*)d_in[4];
  const float* W1   = (const float*)d_in[5];
  const float* b1   = (const float*)d_in[6];
  const float* W2   = (const float*)d_in[7];
  const float* b2   = (const float*)d_in[8];
  const float* g1   = (const float*)d_in[9];
  const float* be1  = (const float*)d_in[10];
  const float* g2   = (const float*)d_in[11];
  const float* be2  = (const float*)d_in[12];
  const float* gf   = (const float*)d_in[13];
  const float* bfb  = (const float*)d_in[14];
  float* out = (float*)d_out;

  const size_t QS = (size_t)CC * 3 * CC;
  const size_t PS = (size_t)CC * CC;
  const size_t S1 = (size_t)CC * DFF;
  const size_t S2 = (size_t)DFF * CC;

  char* p = (char*)d_ws;
  uint16_t* x = (uint16_t*)p;      p += (size_t)MM * CC * 2;        // bf16 residual
  uint16_t* act = (uint16_t*)p;    p += (size_t)MM * CC * 2;
  uint16_t* big = (uint16_t*)p;    p += (size_t)MM * DFF * 2;
  uint16_t* tokb = (uint16_t*)p;   p += (size_t)VV * CC * 2;
  uint16_t* partb = (uint16_t*)p;  p += (size_t)2 * MM * CC * 2;
  char* pbase = p;
  uint16_t* wqA = (uint16_t*)p;    p += QS * LNUM * 2;
  uint16_t* wpA = (uint16_t*)p;    p += PS * LNUM * 2;
  uint16_t* w1A = (uint16_t*)p;    p += S1 * LNUM * 2;
  uint16_t* w2A = (uint16_t*)p;    p += S2 * LNUM * 2;
  const bool roomy2 = ws_size >= (size_t)(p - (char*)d_ws);
  if (!roomy2) {
    p = pbase;
    wqA = (uint16_t*)p; p += QS * 2;
    wpA = (uint16_t*)p; p += PS * 2;
    w1A = (uint16_t*)p; p += S1 * 2;
    w2A = (uint16_t*)p; p += S2 * 2;
  }

  cvt4_k<<<dim3((VV * CC / 4 + 255) / 256), 256, 0, stream>>>(tok, tokb, VV * CC / 4);
  embed_k<<<dim3(MM * (CC / 4) / 256), 256, 0, stream>>>(idx, tok, pos, x);
  ln_k<<<dim3(MM / 4), 256, 0, stream>>>(x, g1, be1, act);
  if (roomy2)
    tca_k<<<dim3(LNUM * 6912), 256, 0, stream>>>(Wqkv, Wpro, W1, W2, wqA, wpA, w1A, w2A);

  for (int l = 0; l < LNUM; ++l) {
    if (!roomy2)
      tca_k<<<dim3(6912), 256, 0, stream>>>(Wqkv + (size_t)l * QS, Wpro + (size_t)l * PS,
                                            W1 + (size_t)l * S1, W2 + (size_t)l * S2,
                                            wqA, wpA, w1A, w2A);
    const size_t lw = roomy2 ? (size_t)l : 0;
    gemm_k<5><<<dim3(MM / 128, 3 * CC / 128, 1), 256, 0, stream>>>(
        act, wqA + lw * QS, 3 * CC, CC, nullptr, big, nullptr);
    attn_k<<<dim3((TT / 64) * BB * HH), 256, 0, stream>>>(big, act);
    gemm_k<8><<<dim3(MM / 128, CC / 128, 2), 256, 0, stream>>>(
        act, wpA + lw * PS, CC, CC, nullptr, partb, nullptr);
    lnrb_k<2><<<dim3(MM / 4), 256, 0, stream>>>(x, partb,
                                                g2 + (size_t)l * CC, be2 + (size_t)l * CC, act);
    gemm_k<2><<<dim3(MM / 128, DFF / 128, 1), 256, 0, stream>>>(
        act, w1A + lw * S1, DFF, CC, b1 + (size_t)l * DFF, big, nullptr);
    const float* ng = (l + 1 < LNUM) ? g1 + (size_t)(l + 1) * CC : gf;
    const float* nb = (l + 1 < LNUM) ? be1 + (size_t)(l + 1) * CC : bfb;
    gemm_k<8><<<dim3(MM / 128, CC / 128, 2), 256, 0, stream>>>(
        big, w2A + lw * S2, CC, DFF, b2 + (size_t)l * CC, partb, nullptr);
    lnrb_k<2><<<dim3(MM / 4), 256, 0, stream>>>(x, partb, ng, nb, act);
  }
  gemm_k<1><<<dim3(MM / 128, VV / 128, 1), 256, 0, stream>>>(
      act, tokb, VV, CC, nullptr, nullptr, out);
}